// Round 13
// baseline (967.882 us; speedup 1.0000x reference)
//
#include <hip/hip_runtime.h>
#include <hip/hip_bf16.h>
#include <math.h>

#define M_ROWS 5792   // B*N
#define NTOK 181
#define NLAYER 6

typedef __attribute__((ext_vector_type(8))) _Float16 f16x8;
typedef __attribute__((ext_vector_type(4))) float f32x4;
typedef __attribute__((ext_vector_type(16))) float f32x16;

__device__ __forceinline__ ushort f2h(float f) {
    union { _Float16 h; ushort u; } v;
    v.h = (_Float16)f;
    return v.u;
}
__device__ __forceinline__ float h2f(ushort u) {
    union { ushort u; _Float16 h; } v; v.u = u;
    return (float)v.h;
}
__device__ __forceinline__ float gelu_f(float v) {
    return 0.5f * v * (1.0f + erff(v * 0.70710678118654752f));
}
__device__ __forceinline__ void async16(const void* g, void* l) {
    __builtin_amdgcn_global_load_lds((const __attribute__((address_space(1))) void*)g,
                                     (__attribute__((address_space(3))) void*)l, 16, 0, 0);
}

// ---------------- weight transpose + f16 convert: W[K][N] f32 -> Wt[N][K] f16 ---
__global__ __launch_bounds__(256) void wt_kernel(const float* __restrict__ W,
                                                 ushort* __restrict__ Wt, int K, int N) {
    __shared__ float t[64][65];
    const size_t ls = (size_t)blockIdx.z * K * N;
    const float* Wl = W + ls;
    ushort* Wtl = Wt + ls;
    const int k0 = blockIdx.x * 64, n0 = blockIdx.y * 64;
    const int tr = threadIdx.x >> 6, tc = threadIdx.x & 63;
    #pragma unroll
    for (int i = 0; i < 16; ++i) {
        const int r = i * 4 + tr;
        t[r][tc] = Wl[(size_t)(k0 + r) * N + n0 + tc];
    }
    __syncthreads();
    #pragma unroll
    for (int i = 0; i < 16; ++i) {
        const int r = i * 4 + tr;
        Wtl[(size_t)(n0 + r) * K + k0 + tc] = f2h(t[tc][r]);
    }
}

// ---------------- x = x0 + pos_embed (f32 + f16 shadow) ----------------
__global__ void add_pos_kernel(const float* __restrict__ x0, const float* __restrict__ pos,
                               float* __restrict__ x, ushort* __restrict__ xb) {
    int idx = blockIdx.x * 256 + threadIdx.x;
    const int total = M_ROWS * 128;
    if (idx >= total) return;
    int col = idx & 127;
    int m   = idx >> 7;
    int t   = m % NTOK;
    float4 a = ((const float4*)x0)[idx];
    float4 p = ((const float4*)pos)[t * 128 + col];
    a.x += p.x; a.y += p.y; a.z += p.z; a.w += p.w;
    ((float4*)x)[idx] = a;
    ((ushort4*)xb)[idx] = make_ushort4(f2h(a.x), f2h(a.y), f2h(a.z), f2h(a.w));
}

// ---------------- f16 MFMA GEMM (round-12): XCD swizzle, no split-K needed ----
template<int BM, int EPI, int SK>
__global__ __launch_bounds__(256) void mfma_gemm(const ushort* __restrict__ A,
                                                 const ushort* __restrict__ Bt,
                                                 const float* __restrict__ bias,
                                                 void* __restrict__ Cv,
                                                 int M, int K, int N) {
    constexpr int MREP = BM / 32;
    __shared__ __align__(16) ushort sA[2][BM * 32];
    __shared__ __align__(16) ushort sB[2][128 * 32];

    const int NC  = N >> 7;
    const int NR  = (M + BM - 1) / BM;
    const int NRP = (NR + 7) & ~7;
    const int PSB = NRP * NC;
    const int gid = blockIdx.x;
    const int sk  = (SK > 1) ? gid / PSB : 0;
    const int j   = (SK > 1) ? gid % PSB : gid;
    const int r   = (j / (8 * NC)) * 8 + (j & 7);
    const int c   = (j % (8 * NC)) >> 3;
    if (r >= NR) return;

    const int tid = threadIdx.x;
    const int lane = tid & 63;
    const int w = tid >> 6;
    const int wr = w >> 1, wc = w & 1;
    const int row0 = r * BM, col0 = c * 128;
    const int wbase = tid & ~63;

    f32x4 acc[MREP][4];
    const f32x4 zero = {0.f, 0.f, 0.f, 0.f};
    #pragma unroll
    for (int m = 0; m < MREP; ++m)
        #pragma unroll
        for (int n = 0; n < 4; ++n) acc[m][n] = zero;

    auto stage = [&](int buf, int kt) {
        const int k0 = kt << 5;
        #pragma unroll
        for (int i = 0; i < BM / 64; ++i) {
            const int s = i * 256 + tid;
            const int row = s >> 2;
            const int kbl = (s & 3) ^ ((row >> 1) & 3);
            int gr = row0 + row; if (gr > M - 1) gr = M - 1;
            async16(A + (size_t)gr * K + k0 + (kbl << 3),
                    &sA[buf][(i * 256 + wbase) * 8]);
        }
        #pragma unroll
        for (int i = 0; i < 2; ++i) {
            const int s = i * 256 + tid;
            const int nr = s >> 2;
            const int kbl = (s & 3) ^ ((nr >> 1) & 3);
            async16(Bt + (size_t)(col0 + nr) * K + k0 + (kbl << 3),
                    &sB[buf][(i * 256 + wbase) * 8]);
        }
    };

    const int NIT = (K / SK) >> 5;
    const int kt0 = sk * NIT;
    stage(0, kt0);
    const int l15 = lane & 15, kb = lane >> 4;
    for (int it = 0; it < NIT; ++it) {
        __syncthreads();
        if (it + 1 < NIT) stage((it + 1) & 1, kt0 + it + 1);
        const int buf = it & 1;
        f16x8 af[MREP], bfr[4];
        #pragma unroll
        for (int m = 0; m < MREP; ++m) {
            const int rr = wr * (BM / 2) + m * 16 + l15;
            af[m] = *(const f16x8*)&sA[buf][rr * 32 + ((kb ^ ((rr >> 1) & 3)) << 3)];
        }
        #pragma unroll
        for (int n = 0; n < 4; ++n) {
            const int rr = wc * 64 + n * 16 + l15;
            bfr[n] = *(const f16x8*)&sB[buf][rr * 32 + ((kb ^ ((rr >> 1) & 3)) << 3)];
        }
        #pragma unroll
        for (int m = 0; m < MREP; ++m)
            #pragma unroll
            for (int n = 0; n < 4; ++n)
                acc[m][n] = __builtin_amdgcn_mfma_f32_16x16x32_f16(af[m], bfr[n], acc[m][n], 0, 0, 0);
    }

    const int crow = row0 + wr * (BM / 2) + (lane >> 4) * 4;
    const int ccol = col0 + wc * 64 + l15;
    ushort* outh = (ushort*)Cv + (size_t)sk * M * N;
    #pragma unroll
    for (int m = 0; m < MREP; ++m)
        #pragma unroll
        for (int n = 0; n < 4; ++n) {
            const int gc = ccol + n * 16;
            const float bv = (SK == 1 || sk == 0) ? bias[gc] : 0.f;
            #pragma unroll
            for (int rr = 0; rr < 4; ++rr) {
                const int gr = crow + m * 16 + rr;
                if (gr < M) {
                    float v = acc[m][n][rr] + bv;
                    if (EPI == 1)      outh[(size_t)gr * N + gc] = f2h(gelu_f(v));
                    else if (EPI == 2) outh[(size_t)gr * N + gc] = f2h(v);
                    else               ((float*)Cv)[(size_t)gr * N + gc] = v;
                }
            }
        }
}

// ===== fused full-row GEMM (N=512) + bias + residual + LayerNorm ==============
// BM=16 rows/block, full N=512 per block, full K contraction -> block owns its
// rows end-to-end; LN done in-block via LDS (no fences, no partials).
__global__ __launch_bounds__(256) void gemm_lnfull(const ushort* __restrict__ A,
                                                   const ushort* __restrict__ Bt,
                                                   const float* __restrict__ bias,
                                                   float* __restrict__ x, ushort* __restrict__ xb,
                                                   const float* __restrict__ g,
                                                   const float* __restrict__ bb,
                                                   int K) {
    __shared__ __align__(16) ushort sA[2][16 * 32];     //  2 KB
    __shared__ __align__(16) ushort sB[2][512 * 32];    // 64 KB
    float* sLN = (float*)&sB[0][0];                     // [16][520] f32, aliases sB

    const int tid = threadIdx.x;
    const int lane = tid & 63;
    const int w = tid >> 6;
    const int l15 = lane & 15, kb = lane >> 4;
    const int wbase = tid & ~63;
    const int row0 = blockIdx.x * 16;

    f32x4 acc[8];
    const f32x4 zero = {0.f, 0.f, 0.f, 0.f};
    #pragma unroll
    for (int n = 0; n < 8; ++n) acc[n] = zero;

    auto stage = [&](int buf, int kt) {
        const int k0 = kt << 5;
        if (w == 0) {                               // A: 16 rows x 4 chunks = 64
            const int row = lane >> 2;
            const int kbl = (lane & 3) ^ ((row >> 1) & 3);
            async16(A + (size_t)(row0 + row) * K + k0 + (kbl << 3), &sA[buf]);
        }
        #pragma unroll
        for (int i = 0; i < 8; ++i) {               // B: 512 rows x 4 chunks
            const int s = i * 256 + tid;
            const int nr = s >> 2;
            const int kbl = (s & 3) ^ ((nr >> 1) & 3);
            async16(Bt + (size_t)nr * K + k0 + (kbl << 3),
                    &sB[buf][(i * 256 + wbase) * 8]);
        }
    };

    const int NIT = K >> 5;
    stage(0, 0);
    for (int it = 0; it < NIT; ++it) {
        __syncthreads();
        if (it + 1 < NIT) stage((it + 1) & 1, it + 1);
        const int buf = it & 1;
        f16x8 af = *(const f16x8*)&sA[buf][l15 * 32 + ((kb ^ ((l15 >> 1) & 3)) << 3)];
        f16x8 bf[8];
        #pragma unroll
        for (int n = 0; n < 8; ++n) {
            const int nr = w * 128 + n * 16 + l15;
            bf[n] = *(const f16x8*)&sB[buf][nr * 32 + ((kb ^ ((nr >> 1) & 3)) << 3)];
        }
        #pragma unroll
        for (int n = 0; n < 8; ++n)
            acc[n] = __builtin_amdgcn_mfma_f32_16x16x32_f16(af, bf[n], acc[n], 0, 0, 0);
    }
    __syncthreads();                  // all sB reads done before aliasing as sLN

    // C/D (row = kb*4+r, col = l15): store bias-added f32 to sLN[16][520]
    #pragma unroll
    for (int n = 0; n < 8; ++n) {
        const int col = w * 128 + n * 16 + l15;
        const float bv = bias[col];
        #pragma unroll
        for (int r = 0; r < 4; ++r)
            sLN[(kb * 4 + r) * 520 + col] = acc[n][r] + bv;
    }
    __syncthreads();

    // LN for 4 rows per wave (verbatim lnres math; y from LDS)
    #pragma unroll 1
    for (int r4 = 0; r4 < 4; ++r4) {
        const int row = w * 4 + r4;
        const int gr = row0 + row;
        float* xr = x + (size_t)gr * 512;
        ushort* xbr = xb + (size_t)gr * 512;
        const float* yr = &sLN[row * 520];
        float4 v0 = *(const float4*)(xr + (lane << 2));
        float4 v1 = *(const float4*)(xr + 256 + (lane << 2));
        const float4 u0 = *(const float4*)(yr + (lane << 2));
        const float4 u1 = *(const float4*)(yr + 256 + (lane << 2));
        v0.x += u0.x; v0.y += u0.y; v0.z += u0.z; v0.w += u0.w;
        v1.x += u1.x; v1.y += u1.y; v1.z += u1.z; v1.w += u1.w;
        float s = v0.x + v0.y + v0.z + v0.w + v1.x + v1.y + v1.z + v1.w;
        #pragma unroll
        for (int off = 32; off; off >>= 1) s += __shfl_xor(s, off);
        const float m = s * (1.0f / 512.0f);
        float d0 = v0.x - m, d1 = v0.y - m, d2 = v0.z - m, d3 = v0.w - m;
        float d4 = v1.x - m, d5 = v1.y - m, d6 = v1.z - m, d7 = v1.w - m;
        float q = d0*d0 + d1*d1 + d2*d2 + d3*d3 + d4*d4 + d5*d5 + d6*d6 + d7*d7;
        #pragma unroll
        for (int off = 32; off; off >>= 1) q += __shfl_xor(q, off);
        const float rq = rsqrtf(q * (1.0f / 512.0f) + 1e-5f);
        const float4 g0 = *(const float4*)(g + (lane << 2));
        const float4 g1 = *(const float4*)(g + 256 + (lane << 2));
        const float4 b0 = *(const float4*)(bb + (lane << 2));
        const float4 b1 = *(const float4*)(bb + 256 + (lane << 2));
        float4 o0, o1;
        o0.x = d0 * rq * g0.x + b0.x; o0.y = d1 * rq * g0.y + b0.y;
        o0.z = d2 * rq * g0.z + b0.z; o0.w = d3 * rq * g0.w + b0.w;
        o1.x = d4 * rq * g1.x + b1.x; o1.y = d5 * rq * g1.y + b1.y;
        o1.z = d6 * rq * g1.z + b1.z; o1.w = d7 * rq * g1.w + b1.w;
        *(float4*)(xr + (lane << 2)) = o0;
        *(float4*)(xr + 256 + (lane << 2)) = o1;
        *(ushort4*)(xbr + (lane << 2)) = make_ushort4(f2h(o0.x), f2h(o0.y), f2h(o0.z), f2h(o0.w));
        *(ushort4*)(xbr + 256 + (lane << 2)) = make_ushort4(f2h(o1.x), f2h(o1.y), f2h(o1.z), f2h(o1.w));
    }
}

// ---------------- head MLP via MFMA ------------------------------------------
__global__ __launch_bounds__(256) void head_mfma(const ushort* __restrict__ A,
                                                 const ushort* __restrict__ Bt,
                                                 const float* __restrict__ b1,
                                                 const float* __restrict__ w2,
                                                 const float* __restrict__ b2,
                                                 float* __restrict__ shift) {
    const int M = M_ROWS, K = 512;
    __shared__ __align__(16) ushort sA[2][128 * 32];
    __shared__ __align__(16) ushort sB[2][64 * 32];
    const int tid = threadIdx.x;
    const int lane = tid & 63;
    const int w = tid >> 6;
    const int row0 = blockIdx.x * 128;
    const int wbase = tid & ~63;

    f32x4 acc[2][4];
    const f32x4 zero = {0.f, 0.f, 0.f, 0.f};
    #pragma unroll
    for (int m = 0; m < 2; ++m)
        #pragma unroll
        for (int n = 0; n < 4; ++n) acc[m][n] = zero;

    auto stage = [&](int buf, int kt) {
        const int k0 = kt << 5;
        #pragma unroll
        for (int i = 0; i < 2; ++i) {
            const int s = i * 256 + tid;
            const int row = s >> 2;
            const int kbl = (s & 3) ^ ((row >> 1) & 3);
            int gr = row0 + row; if (gr > M - 1) gr = M - 1;
            async16(A + (size_t)gr * K + k0 + (kbl << 3),
                    &sA[buf][(i * 256 + wbase) * 8]);
        }
        {
            const int s = tid;
            const int nr = s >> 2;
            const int kbl = (s & 3) ^ ((nr >> 1) & 3);
            async16(Bt + (size_t)nr * K + k0 + (kbl << 3),
                    &sB[buf][wbase * 8]);
        }
    };

    stage(0, 0);
    const int l15 = lane & 15, kb = lane >> 4;
    for (int it = 0; it < 16; ++it) {
        __syncthreads();
        if (it + 1 < 16) stage((it + 1) & 1, it + 1);
        const int buf = it & 1;
        f16x8 af[2], bfr[4];
        #pragma unroll
        for (int m = 0; m < 2; ++m) {
            const int r = w * 32 + m * 16 + l15;
            af[m] = *(const f16x8*)&sA[buf][r * 32 + ((kb ^ ((r >> 1) & 3)) << 3)];
        }
        #pragma unroll
        for (int n = 0; n < 4; ++n) {
            const int r = n * 16 + l15;
            bfr[n] = *(const f16x8*)&sB[buf][r * 32 + ((kb ^ ((r >> 1) & 3)) << 3)];
        }
        #pragma unroll
        for (int m = 0; m < 2; ++m)
            #pragma unroll
            for (int n = 0; n < 4; ++n)
                acc[m][n] = __builtin_amdgcn_mfma_f32_16x16x32_f16(af[m], bfr[n], acc[m][n], 0, 0, 0);
    }

    const float b2v = b2[0];
    float b1v[4], w2v[4];
    #pragma unroll
    for (int n = 0; n < 4; ++n) {
        const int c = n * 16 + l15;
        b1v[n] = b1[c];
        w2v[n] = w2[c];
    }
    #pragma unroll
    for (int m = 0; m < 2; ++m) {
        #pragma unroll
        for (int r = 0; r < 4; ++r) {
            float p = 0.f;
            #pragma unroll
            for (int n = 0; n < 4; ++n)
                p += fmaxf(acc[m][n][r] + b1v[n], 0.f) * w2v[n];
            #pragma unroll
            for (int off = 1; off < 16; off <<= 1) p += __shfl_xor(p, off);
            const int gr = row0 + w * 32 + m * 16 + kb * 4 + r;
            if (l15 == 0 && gr < M) shift[gr] = p + b2v;
        }
    }
}

// ---------------- relative-position bias, all layers ------------------------
__global__ void rbias_kernel(const float* __restrict__ rel_pos, const float* __restrict__ rpe_w,
                             float* __restrict__ r) {
    const int l = blockIdx.y;
    int j = blockIdx.x * 64 + threadIdx.x;
    if (j >= 2 * NTOK - 1) return;
    const float* rp = rel_pos + ((size_t)l * (2 * NTOK - 1) + j) * 64;
    const float* wv = rpe_w + l * 64;
    float s = 0.f;
    #pragma unroll
    for (int d = 0; d < 64; d += 4) {
        float4 a = *(const float4*)(rp + d);
        float4 b = *(const float4*)(wv + d);
        s += a.x*b.x + a.y*b.y + a.z*b.z + a.w*b.w;
    }
    r[l * 512 + j] = s;
}

// ============== FUSED qkv-GEMM + attention: one block per (b,h) ===============
__global__ __launch_bounds__(192, 1) void attn_fused(const ushort* __restrict__ xb,
                                                     const ushort* __restrict__ Wt,
                                                     const float* __restrict__ bias,
                                                     const float* __restrict__ rb,
                                                     ushort* __restrict__ outb) {
    extern __shared__ __align__(16) char smem[];
    ushort* Ks = (ushort*)smem;             // [192][64]
    ushort* Qs = Ks + 12288;                // [192][64]
    ushort* vt = Qs + 12288;                // [64][192]
    ushort* sA = vt + 12288;                // 2 x 192x32
    ushort* sB = sA + 12288;                // 2 x 192x32
    float*  rs = (float*)(smem + 122880);   // 416 floats

    const int b = blockIdx.x >> 3;
    const int h = blockIdx.x & 7;
    const int tid = threadIdx.x, lane = tid & 63, w = tid >> 6;
    const int l31 = lane & 31, hi = lane >> 5;
    const int l15 = lane & 15, kb = lane >> 4;
    const int wbase = tid & ~63;

    for (int i = tid; i < 416; i += 192) {
        int j = i - 32;
        rs[i] = (j >= 0 && j < 2 * NTOK - 1) ? rb[j] : 0.f;
    }

    const ushort* Arow = xb + (size_t)(b * NTOK) * 512;

    auto stage = [&](int buf, int it) {
        const int k0 = it << 5;
        #pragma unroll
        for (int i = 0; i < 4; ++i) {
            const int s = i * 192 + tid;
            const int row = s >> 2;
            const int kbl = (s & 3) ^ ((row >> 1) & 3);
            const int gr = row < NTOK ? row : NTOK - 1;
            async16(Arow + (size_t)gr * 512 + k0 + (kbl << 3),
                    &sA[buf * 6144 + (i * 192 + wbase) * 8]);
        }
        #pragma unroll
        for (int i = 0; i < 4; ++i) {
            const int s = i * 192 + tid;
            const int n = s >> 2;
            const int kbl = (s & 3) ^ ((n >> 1) & 3);
            const int wrow = (n >> 6) * 512 + h * 64 + (n & 63);
            async16(Wt + (size_t)wrow * 512 + k0 + (kbl << 3),
                    &sB[buf * 6144 + (i * 192 + wbase) * 8]);
        }
    };

    // -------- phase 1: GEMM --------
    f32x4 acc[48];
    const f32x4 zero = {0.f, 0.f, 0.f, 0.f};
    #pragma unroll
    for (int t = 0; t < 48; ++t) acc[t] = zero;

    stage(0, 0);
    for (int it = 0; it < 16; ++it) {
        __syncthreads();
        if (it + 1 < 16) stage((it + 1) & 1, it + 1);
        const ushort* a  = &sA[(it & 1) * 6144];
        const ushort* bw = &sB[(it & 1) * 6144];
        if (w < 2) {
            f16x8 af[12], bf[4];
            #pragma unroll
            for (int mt = 0; mt < 12; ++mt) {
                const int r = mt * 16 + l15;
                af[mt] = *(const f16x8*)&a[r * 32 + ((kb ^ ((r >> 1) & 3)) << 3)];
            }
            #pragma unroll
            for (int nt = 0; nt < 4; ++nt) {
                const int n = w * 64 + nt * 16 + l15;
                bf[nt] = *(const f16x8*)&bw[n * 32 + ((kb ^ ((n >> 1) & 3)) << 3)];
            }
            #pragma unroll
            for (int mt = 0; mt < 12; ++mt)
                #pragma unroll
                for (int nt = 0; nt < 4; ++nt)
                    acc[mt * 4 + nt] = __builtin_amdgcn_mfma_f32_16x16x32_f16(af[mt], bf[nt], acc[mt * 4 + nt], 0, 0, 0);
        } else {
            f16x8 af[4], bf[12];
            #pragma unroll
            for (int mt = 0; mt < 4; ++mt) {
                const int n = 128 + mt * 16 + l15;
                af[mt] = *(const f16x8*)&bw[n * 32 + ((kb ^ ((n >> 1) & 3)) << 3)];
            }
            #pragma unroll
            for (int nt = 0; nt < 12; ++nt) {
                const int r = nt * 16 + l15;
                bf[nt] = *(const f16x8*)&a[r * 32 + ((kb ^ ((r >> 1) & 3)) << 3)];
            }
            #pragma unroll
            for (int mt = 0; mt < 4; ++mt)
                #pragma unroll
                for (int nt = 0; nt < 12; ++nt)
                    acc[mt * 12 + nt] = __builtin_amdgcn_mfma_f32_16x16x32_f16(af[mt], bf[nt], acc[mt * 12 + nt], 0, 0, 0);
        }
    }

    if (w < 2) {
        ushort* dst = (w == 0) ? Qs : Ks;
        const int boff = w * 512 + h * 64;
        #pragma unroll
        for (int nt = 0; nt < 4; ++nt) {
            const int d = nt * 16 + l15;
            const float bv = bias[boff + d];
            #pragma unroll
            for (int mt = 0; mt < 12; ++mt)
                #pragma unroll
                for (int r = 0; r < 4; ++r) {
                    const int tok = mt * 16 + kb * 4 + r;
                    dst[tok * 64 + (((d >> 3) ^ (tok & 7)) << 3) + (d & 7)] =
                        f2h(acc[mt * 4 + nt][r] + bv);
                }
        }
    } else {
        #pragma unroll
        for (int mt = 0; mt < 4; ++mt)
            #pragma unroll
            for (int r = 0; r < 4; ++r) {
                const int d = mt * 16 + kb * 4 + r;
                const float bv = bias[1024 + h * 64 + d];
                const int sd = (d ^ (d >> 3)) & 7;
                #pragma unroll
                for (int nt = 0; nt < 12; ++nt) {
                    const int tok = nt * 16 + l15;
                    vt[d * 192 + (((tok >> 3) ^ sd) << 3) + (tok & 7)] =
                        f2h(acc[mt * 12 + nt][r] + bv);
                }
            }
    }
    __syncthreads();

    // -------- phase 2: attention --------
    for (int qt = 0; qt < 2; ++qt) {
        const int q0 = (w + 3 * qt) * 32;
        const int q = q0 + l31;
        f16x8 qf[4];
        #pragma unroll
        for (int ds = 0; ds < 4; ++ds)
            qf[ds] = *(const f16x8*)&Qs[q * 64 + (((2 * ds + hi) ^ (q & 7)) << 3)];

        f32x16 S[6];
        #pragma unroll
        for (int kt = 0; kt < 6; ++kt)
            #pragma unroll
            for (int r = 0; r < 16; ++r) S[kt][r] = 0.f;
        __builtin_amdgcn_s_setprio(1);
        #pragma unroll
        for (int kt = 0; kt < 6; ++kt) {
            const int krow = kt * 32 + l31;
            #pragma unroll
            for (int ds = 0; ds < 4; ++ds) {
                f16x8 kf = *(const f16x8*)&Ks[krow * 64 + (((2 * ds + hi) ^ (krow & 7)) << 3)];
                S[kt] = __builtin_amdgcn_mfma_f32_32x32x16_f16(kf, qf[ds], S[kt], 0, 0, 0);
            }
        }
        __builtin_amdgcn_s_setprio(0);

        float mx = -1e30f;
        #pragma unroll
        for (int kt = 0; kt < 6; ++kt)
            #pragma unroll
            for (int r = 0; r < 16; ++r) {
                const int k = kt * 32 + (r & 3) + 8 * (r >> 2) + 4 * hi;
                float s = (k < NTOK) ? S[kt][r] * 0.125f + rs[k - q + 212] : -1e30f;
                S[kt][r] = s;
                mx = fmaxf(mx, s);
            }
        mx = fmaxf(mx, __shfl_xor(mx, 32));
        float sum = 0.f;
        #pragma unroll
        for (int kt = 0; kt < 6; ++kt)
            #pragma unroll
            for (int r = 0; r < 16; ++r) {
                float e = __expf(S[kt][r] - mx);
                S[kt][r] = e;
                sum += e;
            }
        sum += __shfl_xor(sum, 32);
        const float inv = 1.0f / sum;
        #pragma unroll
        for (int kt = 0; kt < 6; ++kt)
            #pragma unroll
            for (int r = 0; r < 16; ++r) S[kt][r] *= inv;

        f32x16 O[2];
        #pragma unroll
        for (int nt = 0; nt < 2; ++nt)
            #pragma unroll
            for (int r = 0; r < 16; ++r) O[nt][r] = 0.f;
        #pragma unroll
        for (int kt2 = 0; kt2 < 12; ++kt2) {
            const int kt = kt2 >> 1, half = kt2 & 1;
            uint p[4];
            #pragma unroll
            for (int m = 0; m < 4; ++m)
                p[m] = (uint)f2h(S[kt][8 * half + 2 * m]) |
                       ((uint)f2h(S[kt][8 * half + 2 * m + 1]) << 16);
            const uint s0l = (uint)__shfl_xor((int)p[0], 32);
            const uint s0h = (uint)__shfl_xor((int)p[1], 32);
            const uint s1l = (uint)__shfl_xor((int)p[2], 32);
            const uint s1h = (uint)__shfl_xor((int)p[3], 32);
            uint fa[4];
            if (hi == 0) { fa[0] = p[0]; fa[1] = p[1]; fa[2] = s0l; fa[3] = s0h; }
            else         { fa[0] = s1l; fa[1] = s1h; fa[2] = p[2]; fa[3] = p[3]; }
            const f16x8 pa = *(const f16x8*)fa;
            __builtin_amdgcn_s_setprio(1);
            #pragma unroll
            for (int nt = 0; nt < 2; ++nt) {
                const int d = nt * 32 + l31;
                f16x8 vf = *(const f16x8*)&vt[d * 192 + (((2 * kt2 + hi) ^ ((d ^ (d >> 3)) & 7)) << 3)];
                O[nt] = __builtin_amdgcn_mfma_f32_32x32x16_f16(pa, vf, O[nt], 0, 0, 0);
            }
            __builtin_amdgcn_s_setprio(0);
        }

        #pragma unroll
        for (int nt = 0; nt < 2; ++nt)
            #pragma unroll
            for (int r = 0; r < 16; ++r) {
                const int qr = q0 + (r & 3) + 8 * (r >> 2) + 4 * hi;
                if (qr < NTOK)
                    outb[(size_t)(b * NTOK + qr) * 512 + h * 64 + nt * 32 + l31] = f2h(O[nt][r]);
            }
    }
}

// ---------------- bilinear warp ----------------------------------------------
__global__ void warp_kernel(const float* __restrict__ x0, const float* __restrict__ shift,
                            const int* __restrict__ pms, float* __restrict__ warped) {
    int idx = blockIdx.x * 256 + threadIdx.x;
    if (idx >= M_ROWS * 512) return;
    int c = idx & 511;
    int m = idx >> 9;
    int t = m % NTOK;
    int b = m / NTOK;
    float max_shift = (float)pms[0];
    float sh = shift[m];
    float flow = sh * max_shift / 256.0f;
    float gx = 2.0f * ((float)c / 511.0f - 0.5f) + flow;
    float ix = ((gx + 1.0f) * 512.0f - 1.0f) * 0.5f;
    ix = fminf(fmaxf(ix, 0.0f), 511.0f);
    float gy = 2.0f * ((float)t / 180.0f - 0.5f);
    float iy = ((gy + 1.0f) * 181.0f - 1.0f) * 0.5f;
    iy = fminf(fmaxf(iy, 0.0f), 180.0f);
    float ix0f = floorf(ix), iy0f = floorf(iy);
    float wx = ix - ix0f, wy = iy - iy0f;
    int ix0 = min(max((int)ix0f, 0), 511);
    int ix1 = min(ix0 + 1, 511);
    int iy0 = min(max((int)iy0f, 0), 180);
    int iy1 = min(iy0 + 1, 180);
    const float* xb = x0 + (size_t)b * NTOK * 512;
    float v00 = xb[iy0 * 512 + ix0], v01 = xb[iy0 * 512 + ix1];
    float v10 = xb[iy1 * 512 + ix0], v11 = xb[iy1 * 512 + ix1];
    warped[idx] = (1.f - wy) * ((1.f - wx) * v00 + wx * v01) + wy * ((1.f - wx) * v10 + wx * v11);
}

extern "C" void kernel_launch(void* const* d_in, const int* in_sizes, int n_in,
                              void* d_out, int out_size, void* d_ws, size_t ws_size,
                              hipStream_t stream) {
    const float* x0   = (const float*)d_in[0];
    const int*   pms  = (const int*)d_in[1];
    const float* pos  = (const float*)d_in[2];
    const float* qkvw = (const float*)d_in[3];
    const float* qkvb = (const float*)d_in[4];
    const float* outw = (const float*)d_in[5];
    const float* outbp= (const float*)d_in[6];
    const float* relp = (const float*)d_in[7];
    const float* rpew = (const float*)d_in[8];
    const float* ln1g = (const float*)d_in[9];
    const float* ln1b = (const float*)d_in[10];
    const float* fw1  = (const float*)d_in[11];
    const float* fb1  = (const float*)d_in[12];
    const float* fw2  = (const float*)d_in[13];
    const float* fb2  = (const float*)d_in[14];
    const float* ln2g = (const float*)d_in[15];
    const float* ln2b = (const float*)d_in[16];
    const float* mw1  = (const float*)d_in[17];
    const float* mb1  = (const float*)d_in[18];
    const float* mw2  = (const float*)d_in[19];
    const float* mb2  = (const float*)d_in[20];

    float* out = (float*)d_out;

    char* ws = (char*)d_ws;
    float*  x     = (float*)ws;                               // 11,862,016 B
    ushort* xb    = (ushort*)(ws + 11862016);                 //  5,931,008 B
    char*   qr    = ws + 11862016 + 5931008;
    ushort* hbuf  = (ushort*)(qr + 11862016);                 // 23.7MB (ffn hidden)
    ushort* attnb = (ushort*)(qr + 35586048);                 //  5,931,008 B
    float*  rbias = (float*)(qr + 35586048 + 5931008);        //  6*512*4 B
    ushort* wts   = (ushort*)(qr + 35586048 + 5931008 + 12288);
    ushort* qkv_wt = wts;                                     // 6*1536*512
    ushort* out_wt = qkv_wt + 6 * 1536 * 512;                 // 6*512*512
    ushort* f1_wt  = out_wt + 6 * 512 * 512;                  // 6*2048*512
    ushort* f2_wt  = f1_wt  + 6 * 512 * 2048;                 // 6*512*2048
    ushort* w1t    = f2_wt  + 6 * 2048 * 512;                 // 64*512

    hipFuncSetAttribute((const void*)attn_fused,
                        hipFuncAttributeMaxDynamicSharedMemorySize, 124544);

    // preprocess weights: f32 [K][N] -> f16 [N][K]
    wt_kernel<<<dim3(8, 24, 6), 256, 0, stream>>>(qkvw, qkv_wt, 512, 1536);
    wt_kernel<<<dim3(8,  8, 6), 256, 0, stream>>>(outw, out_wt, 512, 512);
    wt_kernel<<<dim3(8, 32, 6), 256, 0, stream>>>(fw1,  f1_wt,  512, 2048);
    wt_kernel<<<dim3(32, 8, 6), 256, 0, stream>>>(fw2,  f2_wt,  2048, 512);
    wt_kernel<<<dim3(8,  1, 1), 256, 0, stream>>>(mw1,  w1t,    512, 64);
    rbias_kernel<<<dim3(6, 6), 64, 0, stream>>>(relp, rpew, rbias);

    add_pos_kernel<<<(M_ROWS * 128 + 255) / 256, 256, 0, stream>>>(x0, pos, x, xb);

    const int g_ffn1 = 96 * 16;        // BM=64, N=2048
    for (int i = 0; i < NLAYER; ++i) {
        attn_fused<<<256, 192, 124544, stream>>>(xb, qkv_wt + (size_t)i * 1536 * 512,
                                                 qkvb + i * 1536, rbias + i * 512, attnb);
        gemm_lnfull<<<362, 256, 0, stream>>>(attnb, out_wt + (size_t)i * 512 * 512,
                                             outbp + i * 512, x, xb,
                                             ln1g + i * 512, ln1b + i * 512, 512);
        mfma_gemm<64, 1, 1><<<g_ffn1, 256, 0, stream>>>(xb, f1_wt + (size_t)i * 2048 * 512,
                                                        fb1 + i * 2048, hbuf, M_ROWS, 512, 2048);
        gemm_lnfull<<<362, 256, 0, stream>>>(hbuf, f2_wt + (size_t)i * 512 * 2048,
                                             fb2 + i * 512, x, xb,
                                             ln2g + i * 512, ln2b + i * 512, 2048);
    }

    head_mfma<<<46, 256, 0, stream>>>(xb, w1t, mb1, mw2, mb2, out);
    warp_kernel<<<(M_ROWS * 512 + 255) / 256, 256, 0, stream>>>(x0, out, pms, out + M_ROWS);
}

// Round 14
// 725.967 us; speedup vs baseline: 1.3332x; 1.3332x over previous
//
#include <hip/hip_runtime.h>
#include <hip/hip_bf16.h>
#include <math.h>

#define M_ROWS 5792   // B*N
#define NTOK 181
#define NLAYER 6

typedef __attribute__((ext_vector_type(8))) _Float16 f16x8;
typedef __attribute__((ext_vector_type(4))) float f32x4;
typedef __attribute__((ext_vector_type(16))) float f32x16;

__device__ __forceinline__ ushort f2h(float f) {
    union { _Float16 h; ushort u; } v;
    v.h = (_Float16)f;
    return v.u;
}
__device__ __forceinline__ float h2f(ushort u) {
    union { ushort u; _Float16 h; } v; v.u = u;
    return (float)v.h;
}
__device__ __forceinline__ float gelu_f(float v) {
    return 0.5f * v * (1.0f + erff(v * 0.70710678118654752f));
}
__device__ __forceinline__ void async16(const void* g, void* l) {
    __builtin_amdgcn_global_load_lds((const __attribute__((address_space(1))) void*)g,
                                     (__attribute__((address_space(3))) void*)l, 16, 0, 0);
}

// ---- combined weight prep: 5 transposes (f32 [K][N] -> f16 [N][K]) + rbias ----
// blocks [0,1152) qkv | [1152,1536) out | [1536,3072) ffn1 | [3072,4608) ffn2 |
// [4608,4616) mlp_w1 | [4616,4628) rbias (2 blocks x 6 layers)
__global__ __launch_bounds__(256) void wt_all(const float* __restrict__ qkvw,
                                              const float* __restrict__ outw,
                                              const float* __restrict__ fw1,
                                              const float* __restrict__ fw2,
                                              const float* __restrict__ mw1,
                                              const float* __restrict__ relp,
                                              const float* __restrict__ rpew,
                                              ushort* __restrict__ qkv_wt, ushort* __restrict__ out_wt,
                                              ushort* __restrict__ f1_wt, ushort* __restrict__ f2_wt,
                                              ushort* __restrict__ w1t, float* __restrict__ rbias) {
    int id = blockIdx.x;
    if (id >= 4616) {                      // rbias: r[l][j] = dot(rel_pos[l][j], rpe_w[l])
        id -= 4616;
        const int l = id >> 1;
        const int j = (id & 1) * 256 + threadIdx.x;
        if (j >= 2 * NTOK - 1) return;
        const float* rp = relp + ((size_t)l * (2 * NTOK - 1) + j) * 64;
        const float* wv = rpew + l * 64;
        float s = 0.f;
        #pragma unroll
        for (int d = 0; d < 64; d += 4) {
            float4 a = *(const float4*)(rp + d);
            float4 b = *(const float4*)(wv + d);
            s += a.x*b.x + a.y*b.y + a.z*b.z + a.w*b.w;
        }
        rbias[l * 512 + j] = s;
        return;
    }
    const float* W; ushort* Wt; int K, N;
    if (id < 1152)      { W = qkvw; Wt = qkv_wt; K = 512;  N = 1536; }
    else if (id < 1536) { W = outw; Wt = out_wt; K = 512;  N = 512;  id -= 1152; }
    else if (id < 3072) { W = fw1;  Wt = f1_wt;  K = 512;  N = 2048; id -= 1536; }
    else if (id < 4608) { W = fw2;  Wt = f2_wt;  K = 2048; N = 512;  id -= 3072; }
    else                { W = mw1;  Wt = w1t;    K = 512;  N = 64;   id -= 4608; }
    const int nk = K >> 6, nn = N >> 6;
    const int per = nk * nn;
    const int z = id / per; id -= z * per;
    const int k0 = (id % nk) * 64, n0 = (id / nk) * 64;

    __shared__ float t[64][65];
    const size_t ls = (size_t)z * K * N;
    const float* Wl = W + ls;
    ushort* Wtl = Wt + ls;
    const int tr = threadIdx.x >> 6, tc = threadIdx.x & 63;
    #pragma unroll
    for (int i = 0; i < 16; ++i) {
        const int r = i * 4 + tr;
        t[r][tc] = Wl[(size_t)(k0 + r) * N + n0 + tc];
    }
    __syncthreads();
    #pragma unroll
    for (int i = 0; i < 16; ++i) {
        const int r = i * 4 + tr;
        Wtl[(size_t)(n0 + r) * K + k0 + tc] = f2h(t[tc][r]);
    }
}

// ---------------- x = x0 + pos_embed (f32 + f16 shadow) ----------------
__global__ void add_pos_kernel(const float* __restrict__ x0, const float* __restrict__ pos,
                               float* __restrict__ x, ushort* __restrict__ xb) {
    int idx = blockIdx.x * 256 + threadIdx.x;
    const int total = M_ROWS * 128;
    if (idx >= total) return;
    int col = idx & 127;
    int m   = idx >> 7;
    int t   = m % NTOK;
    float4 a = ((const float4*)x0)[idx];
    float4 p = ((const float4*)pos)[t * 128 + col];
    a.x += p.x; a.y += p.y; a.z += p.z; a.w += p.w;
    ((float4*)x)[idx] = a;
    ((ushort4*)xb)[idx] = make_ushort4(f2h(a.x), f2h(a.y), f2h(a.z), f2h(a.w));
}

// ---------------- f16 MFMA GEMM: XCD swizzle, optional split-K ----------------
template<int BM, int EPI, int SK>
__global__ __launch_bounds__(256) void mfma_gemm(const ushort* __restrict__ A,
                                                 const ushort* __restrict__ Bt,
                                                 const float* __restrict__ bias,
                                                 void* __restrict__ Cv,
                                                 int M, int K, int N) {
    constexpr int MREP = BM / 32;
    __shared__ __align__(16) ushort sA[2][BM * 32];
    __shared__ __align__(16) ushort sB[2][128 * 32];

    const int NC  = N >> 7;
    const int NR  = (M + BM - 1) / BM;
    const int NRP = (NR + 7) & ~7;
    const int PSB = NRP * NC;
    const int gid = blockIdx.x;
    const int sk  = (SK > 1) ? gid / PSB : 0;
    const int j   = (SK > 1) ? gid % PSB : gid;
    const int r   = (j / (8 * NC)) * 8 + (j & 7);
    const int c   = (j % (8 * NC)) >> 3;
    if (r >= NR) return;

    const int tid = threadIdx.x;
    const int lane = tid & 63;
    const int w = tid >> 6;
    const int wr = w >> 1, wc = w & 1;
    const int row0 = r * BM, col0 = c * 128;
    const int wbase = tid & ~63;

    f32x4 acc[MREP][4];
    const f32x4 zero = {0.f, 0.f, 0.f, 0.f};
    #pragma unroll
    for (int m = 0; m < MREP; ++m)
        #pragma unroll
        for (int n = 0; n < 4; ++n) acc[m][n] = zero;

    auto stage = [&](int buf, int kt) {
        const int k0 = kt << 5;
        #pragma unroll
        for (int i = 0; i < BM / 64; ++i) {
            const int s = i * 256 + tid;
            const int row = s >> 2;
            const int kbl = (s & 3) ^ ((row >> 1) & 3);
            int gr = row0 + row; if (gr > M - 1) gr = M - 1;
            async16(A + (size_t)gr * K + k0 + (kbl << 3),
                    &sA[buf][(i * 256 + wbase) * 8]);
        }
        #pragma unroll
        for (int i = 0; i < 2; ++i) {
            const int s = i * 256 + tid;
            const int nr = s >> 2;
            const int kbl = (s & 3) ^ ((nr >> 1) & 3);
            async16(Bt + (size_t)(col0 + nr) * K + k0 + (kbl << 3),
                    &sB[buf][(i * 256 + wbase) * 8]);
        }
    };

    const int NIT = (K / SK) >> 5;
    const int kt0 = sk * NIT;
    stage(0, kt0);
    const int l15 = lane & 15, kb = lane >> 4;
    for (int it = 0; it < NIT; ++it) {
        __syncthreads();
        if (it + 1 < NIT) stage((it + 1) & 1, kt0 + it + 1);
        const int buf = it & 1;
        f16x8 af[MREP], bfr[4];
        #pragma unroll
        for (int m = 0; m < MREP; ++m) {
            const int rr = wr * (BM / 2) + m * 16 + l15;
            af[m] = *(const f16x8*)&sA[buf][rr * 32 + ((kb ^ ((rr >> 1) & 3)) << 3)];
        }
        #pragma unroll
        for (int n = 0; n < 4; ++n) {
            const int rr = wc * 64 + n * 16 + l15;
            bfr[n] = *(const f16x8*)&sB[buf][rr * 32 + ((kb ^ ((rr >> 1) & 3)) << 3)];
        }
        #pragma unroll
        for (int m = 0; m < MREP; ++m)
            #pragma unroll
            for (int n = 0; n < 4; ++n)
                acc[m][n] = __builtin_amdgcn_mfma_f32_16x16x32_f16(af[m], bfr[n], acc[m][n], 0, 0, 0);
    }

    const int crow = row0 + wr * (BM / 2) + (lane >> 4) * 4;
    const int ccol = col0 + wc * 64 + l15;
    ushort* outh = (ushort*)Cv + (size_t)sk * M * N;
    #pragma unroll
    for (int m = 0; m < MREP; ++m)
        #pragma unroll
        for (int n = 0; n < 4; ++n) {
            const int gc = ccol + n * 16;
            const float bv = (SK == 1 || sk == 0) ? bias[gc] : 0.f;
            #pragma unroll
            for (int rr = 0; rr < 4; ++rr) {
                const int gr = crow + m * 16 + rr;
                if (gr < M) {
                    float v = acc[m][n][rr] + bv;
                    if (EPI == 1)      outh[(size_t)gr * N + gc] = f2h(gelu_f(v));
                    else if (EPI == 2) outh[(size_t)gr * N + gc] = f2h(v);
                    else               ((float*)Cv)[(size_t)gr * N + gc] = v;
                }
            }
        }
}

// ---------------- head MLP via MFMA ------------------------------------------
__global__ __launch_bounds__(256) void head_mfma(const ushort* __restrict__ A,
                                                 const ushort* __restrict__ Bt,
                                                 const float* __restrict__ b1,
                                                 const float* __restrict__ w2,
                                                 const float* __restrict__ b2,
                                                 float* __restrict__ shift) {
    const int M = M_ROWS, K = 512;
    __shared__ __align__(16) ushort sA[2][128 * 32];
    __shared__ __align__(16) ushort sB[2][64 * 32];
    const int tid = threadIdx.x;
    const int lane = tid & 63;
    const int w = tid >> 6;
    const int row0 = blockIdx.x * 128;
    const int wbase = tid & ~63;

    f32x4 acc[2][4];
    const f32x4 zero = {0.f, 0.f, 0.f, 0.f};
    #pragma unroll
    for (int m = 0; m < 2; ++m)
        #pragma unroll
        for (int n = 0; n < 4; ++n) acc[m][n] = zero;

    auto stage = [&](int buf, int kt) {
        const int k0 = kt << 5;
        #pragma unroll
        for (int i = 0; i < 2; ++i) {
            const int s = i * 256 + tid;
            const int row = s >> 2;
            const int kbl = (s & 3) ^ ((row >> 1) & 3);
            int gr = row0 + row; if (gr > M - 1) gr = M - 1;
            async16(A + (size_t)gr * K + k0 + (kbl << 3),
                    &sA[buf][(i * 256 + wbase) * 8]);
        }
        {
            const int s = tid;
            const int nr = s >> 2;
            const int kbl = (s & 3) ^ ((nr >> 1) & 3);
            async16(Bt + (size_t)nr * K + k0 + (kbl << 3),
                    &sB[buf][wbase * 8]);
        }
    };

    stage(0, 0);
    const int l15 = lane & 15, kb = lane >> 4;
    for (int it = 0; it < 16; ++it) {
        __syncthreads();
        if (it + 1 < 16) stage((it + 1) & 1, it + 1);
        const int buf = it & 1;
        f16x8 af[2], bfr[4];
        #pragma unroll
        for (int m = 0; m < 2; ++m) {
            const int r = w * 32 + m * 16 + l15;
            af[m] = *(const f16x8*)&sA[buf][r * 32 + ((kb ^ ((r >> 1) & 3)) << 3)];
        }
        #pragma unroll
        for (int n = 0; n < 4; ++n) {
            const int r = n * 16 + l15;
            bfr[n] = *(const f16x8*)&sB[buf][r * 32 + ((kb ^ ((r >> 1) & 3)) << 3)];
        }
        #pragma unroll
        for (int m = 0; m < 2; ++m)
            #pragma unroll
            for (int n = 0; n < 4; ++n)
                acc[m][n] = __builtin_amdgcn_mfma_f32_16x16x32_f16(af[m], bfr[n], acc[m][n], 0, 0, 0);
    }

    const float b2v = b2[0];
    float b1v[4], w2v[4];
    #pragma unroll
    for (int n = 0; n < 4; ++n) {
        const int c = n * 16 + l15;
        b1v[n] = b1[c];
        w2v[n] = w2[c];
    }
    #pragma unroll
    for (int m = 0; m < 2; ++m) {
        #pragma unroll
        for (int r = 0; r < 4; ++r) {
            float p = 0.f;
            #pragma unroll
            for (int n = 0; n < 4; ++n)
                p += fmaxf(acc[m][n][r] + b1v[n], 0.f) * w2v[n];
            #pragma unroll
            for (int off = 1; off < 16; off <<= 1) p += __shfl_xor(p, off);
            const int gr = row0 + w * 32 + m * 16 + kb * 4 + r;
            if (l15 == 0 && gr < M) shift[gr] = p + b2v;
        }
    }
}

// ============== FUSED qkv-GEMM + attention: one block per (b,h) ===============
__global__ __launch_bounds__(192, 1) void attn_fused(const ushort* __restrict__ xb,
                                                     const ushort* __restrict__ Wt,
                                                     const float* __restrict__ bias,
                                                     const float* __restrict__ rb,
                                                     ushort* __restrict__ outb) {
    extern __shared__ __align__(16) char smem[];
    ushort* Ks = (ushort*)smem;             // [192][64]
    ushort* Qs = Ks + 12288;                // [192][64]
    ushort* vt = Qs + 12288;                // [64][192]
    ushort* sA = vt + 12288;                // 2 x 192x32
    ushort* sB = sA + 12288;                // 2 x 192x32
    float*  rs = (float*)(smem + 122880);   // 416 floats

    const int b = blockIdx.x >> 3;
    const int h = blockIdx.x & 7;
    const int tid = threadIdx.x, lane = tid & 63, w = tid >> 6;
    const int l31 = lane & 31, hi = lane >> 5;
    const int l15 = lane & 15, kb = lane >> 4;
    const int wbase = tid & ~63;

    for (int i = tid; i < 416; i += 192) {
        int j = i - 32;
        rs[i] = (j >= 0 && j < 2 * NTOK - 1) ? rb[j] : 0.f;
    }

    const ushort* Arow = xb + (size_t)(b * NTOK) * 512;

    auto stage = [&](int buf, int it) {
        const int k0 = it << 5;
        #pragma unroll
        for (int i = 0; i < 4; ++i) {
            const int s = i * 192 + tid;
            const int row = s >> 2;
            const int kbl = (s & 3) ^ ((row >> 1) & 3);
            const int gr = row < NTOK ? row : NTOK - 1;
            async16(Arow + (size_t)gr * 512 + k0 + (kbl << 3),
                    &sA[buf * 6144 + (i * 192 + wbase) * 8]);
        }
        #pragma unroll
        for (int i = 0; i < 4; ++i) {
            const int s = i * 192 + tid;
            const int n = s >> 2;
            const int kbl = (s & 3) ^ ((n >> 1) & 3);
            const int wrow = (n >> 6) * 512 + h * 64 + (n & 63);
            async16(Wt + (size_t)wrow * 512 + k0 + (kbl << 3),
                    &sB[buf * 6144 + (i * 192 + wbase) * 8]);
        }
    };

    // -------- phase 1: GEMM --------
    f32x4 acc[48];
    const f32x4 zero = {0.f, 0.f, 0.f, 0.f};
    #pragma unroll
    for (int t = 0; t < 48; ++t) acc[t] = zero;

    stage(0, 0);
    for (int it = 0; it < 16; ++it) {
        __syncthreads();
        if (it + 1 < 16) stage((it + 1) & 1, it + 1);
        const ushort* a  = &sA[(it & 1) * 6144];
        const ushort* bw = &sB[(it & 1) * 6144];
        if (w < 2) {
            f16x8 af[12], bf[4];
            #pragma unroll
            for (int mt = 0; mt < 12; ++mt) {
                const int r = mt * 16 + l15;
                af[mt] = *(const f16x8*)&a[r * 32 + ((kb ^ ((r >> 1) & 3)) << 3)];
            }
            #pragma unroll
            for (int nt = 0; nt < 4; ++nt) {
                const int n = w * 64 + nt * 16 + l15;
                bf[nt] = *(const f16x8*)&bw[n * 32 + ((kb ^ ((n >> 1) & 3)) << 3)];
            }
            #pragma unroll
            for (int mt = 0; mt < 12; ++mt)
                #pragma unroll
                for (int nt = 0; nt < 4; ++nt)
                    acc[mt * 4 + nt] = __builtin_amdgcn_mfma_f32_16x16x32_f16(af[mt], bf[nt], acc[mt * 4 + nt], 0, 0, 0);
        } else {
            f16x8 af[4], bf[12];
            #pragma unroll
            for (int mt = 0; mt < 4; ++mt) {
                const int n = 128 + mt * 16 + l15;
                af[mt] = *(const f16x8*)&bw[n * 32 + ((kb ^ ((n >> 1) & 3)) << 3)];
            }
            #pragma unroll
            for (int nt = 0; nt < 12; ++nt) {
                const int r = nt * 16 + l15;
                bf[nt] = *(const f16x8*)&a[r * 32 + ((kb ^ ((r >> 1) & 3)) << 3)];
            }
            #pragma unroll
            for (int mt = 0; mt < 4; ++mt)
                #pragma unroll
                for (int nt = 0; nt < 12; ++nt)
                    acc[mt * 12 + nt] = __builtin_amdgcn_mfma_f32_16x16x32_f16(af[mt], bf[nt], acc[mt * 12 + nt], 0, 0, 0);
        }
    }

    if (w < 2) {
        ushort* dst = (w == 0) ? Qs : Ks;
        const int boff = w * 512 + h * 64;
        #pragma unroll
        for (int nt = 0; nt < 4; ++nt) {
            const int d = nt * 16 + l15;
            const float bv = bias[boff + d];
            #pragma unroll
            for (int mt = 0; mt < 12; ++mt)
                #pragma unroll
                for (int r = 0; r < 4; ++r) {
                    const int tok = mt * 16 + kb * 4 + r;
                    dst[tok * 64 + (((d >> 3) ^ (tok & 7)) << 3) + (d & 7)] =
                        f2h(acc[mt * 4 + nt][r] + bv);
                }
        }
    } else {
        #pragma unroll
        for (int mt = 0; mt < 4; ++mt)
            #pragma unroll
            for (int r = 0; r < 4; ++r) {
                const int d = mt * 16 + kb * 4 + r;
                const float bv = bias[1024 + h * 64 + d];
                const int sd = (d ^ (d >> 3)) & 7;
                #pragma unroll
                for (int nt = 0; nt < 12; ++nt) {
                    const int tok = nt * 16 + l15;
                    vt[d * 192 + (((tok >> 3) ^ sd) << 3) + (tok & 7)] =
                        f2h(acc[mt * 12 + nt][r] + bv);
                }
            }
    }
    __syncthreads();

    // -------- phase 2: attention --------
    for (int qt = 0; qt < 2; ++qt) {
        const int q0 = (w + 3 * qt) * 32;
        const int q = q0 + l31;
        f16x8 qf[4];
        #pragma unroll
        for (int ds = 0; ds < 4; ++ds)
            qf[ds] = *(const f16x8*)&Qs[q * 64 + (((2 * ds + hi) ^ (q & 7)) << 3)];

        f32x16 S[6];
        #pragma unroll
        for (int kt = 0; kt < 6; ++kt)
            #pragma unroll
            for (int r = 0; r < 16; ++r) S[kt][r] = 0.f;
        __builtin_amdgcn_s_setprio(1);
        #pragma unroll
        for (int kt = 0; kt < 6; ++kt) {
            const int krow = kt * 32 + l31;
            #pragma unroll
            for (int ds = 0; ds < 4; ++ds) {
                f16x8 kf = *(const f16x8*)&Ks[krow * 64 + (((2 * ds + hi) ^ (krow & 7)) << 3)];
                S[kt] = __builtin_amdgcn_mfma_f32_32x32x16_f16(kf, qf[ds], S[kt], 0, 0, 0);
            }
        }
        __builtin_amdgcn_s_setprio(0);

        float mx = -1e30f;
        #pragma unroll
        for (int kt = 0; kt < 6; ++kt)
            #pragma unroll
            for (int r = 0; r < 16; ++r) {
                const int k = kt * 32 + (r & 3) + 8 * (r >> 2) + 4 * hi;
                float s = (k < NTOK) ? S[kt][r] * 0.125f + rs[k - q + 212] : -1e30f;
                S[kt][r] = s;
                mx = fmaxf(mx, s);
            }
        mx = fmaxf(mx, __shfl_xor(mx, 32));
        float sum = 0.f;
        #pragma unroll
        for (int kt = 0; kt < 6; ++kt)
            #pragma unroll
            for (int r = 0; r < 16; ++r) {
                float e = __expf(S[kt][r] - mx);
                S[kt][r] = e;
                sum += e;
            }
        sum += __shfl_xor(sum, 32);
        const float inv = 1.0f / sum;
        #pragma unroll
        for (int kt = 0; kt < 6; ++kt)
            #pragma unroll
            for (int r = 0; r < 16; ++r) S[kt][r] *= inv;

        f32x16 O[2];
        #pragma unroll
        for (int nt = 0; nt < 2; ++nt)
            #pragma unroll
            for (int r = 0; r < 16; ++r) O[nt][r] = 0.f;
        #pragma unroll
        for (int kt2 = 0; kt2 < 12; ++kt2) {
            const int kt = kt2 >> 1, half = kt2 & 1;
            uint p[4];
            #pragma unroll
            for (int m = 0; m < 4; ++m)
                p[m] = (uint)f2h(S[kt][8 * half + 2 * m]) |
                       ((uint)f2h(S[kt][8 * half + 2 * m + 1]) << 16);
            const uint s0l = (uint)__shfl_xor((int)p[0], 32);
            const uint s0h = (uint)__shfl_xor((int)p[1], 32);
            const uint s1l = (uint)__shfl_xor((int)p[2], 32);
            const uint s1h = (uint)__shfl_xor((int)p[3], 32);
            uint fa[4];
            if (hi == 0) { fa[0] = p[0]; fa[1] = p[1]; fa[2] = s0l; fa[3] = s0h; }
            else         { fa[0] = s1l; fa[1] = s1h; fa[2] = p[2]; fa[3] = p[3]; }
            const f16x8 pa = *(const f16x8*)fa;
            __builtin_amdgcn_s_setprio(1);
            #pragma unroll
            for (int nt = 0; nt < 2; ++nt) {
                const int d = nt * 32 + l31;
                f16x8 vf = *(const f16x8*)&vt[d * 192 + (((2 * kt2 + hi) ^ ((d ^ (d >> 3)) & 7)) << 3)];
                O[nt] = __builtin_amdgcn_mfma_f32_32x32x16_f16(pa, vf, O[nt], 0, 0, 0);
            }
            __builtin_amdgcn_s_setprio(0);
        }

        #pragma unroll
        for (int nt = 0; nt < 2; ++nt)
            #pragma unroll
            for (int r = 0; r < 16; ++r) {
                const int qr = q0 + (r & 3) + 8 * (r >> 2) + 4 * hi;
                if (qr < NTOK)
                    outb[(size_t)(b * NTOK + qr) * 512 + h * 64 + nt * 32 + l31] = f2h(O[nt][r]);
            }
    }
}

// ---------------- x = LayerNorm(x + y0 + y1) * g + b ; writes f32 x, f16 xb ----
template<int NY>
__global__ __launch_bounds__(256) void lnres_kernel(float* __restrict__ x, ushort* __restrict__ xb,
                                                    const ushort* __restrict__ y,
                                                    const ushort* __restrict__ y1,
                                                    const float* __restrict__ g, const float* __restrict__ bb) {
    const int row = blockIdx.x * 4 + (threadIdx.x >> 6);
    const int l = threadIdx.x & 63;
    float* xr = x + (size_t)row * 512;
    ushort* xbr = xb + (size_t)row * 512;
    const ushort* yr = y + (size_t)row * 512;
    float4 v0 = *(const float4*)(xr + (l << 2));
    float4 v1 = *(const float4*)(xr + 256 + (l << 2));
    const ushort4 u0 = *(const ushort4*)(yr + (l << 2));
    const ushort4 u1 = *(const ushort4*)(yr + 256 + (l << 2));
    v0.x += h2f(u0.x); v0.y += h2f(u0.y); v0.z += h2f(u0.z); v0.w += h2f(u0.w);
    v1.x += h2f(u1.x); v1.y += h2f(u1.y); v1.z += h2f(u1.z); v1.w += h2f(u1.w);
    if (NY == 2) {
        const ushort* y1r = y1 + (size_t)row * 512;
        const ushort4 w0 = *(const ushort4*)(y1r + (l << 2));
        const ushort4 w1 = *(const ushort4*)(y1r + 256 + (l << 2));
        v0.x += h2f(w0.x); v0.y += h2f(w0.y); v0.z += h2f(w0.z); v0.w += h2f(w0.w);
        v1.x += h2f(w1.x); v1.y += h2f(w1.y); v1.z += h2f(w1.z); v1.w += h2f(w1.w);
    }
    float s = v0.x + v0.y + v0.z + v0.w + v1.x + v1.y + v1.z + v1.w;
    #pragma unroll
    for (int off = 32; off; off >>= 1) s += __shfl_xor(s, off);
    const float m = s * (1.0f / 512.0f);
    float d0 = v0.x - m, d1 = v0.y - m, d2 = v0.z - m, d3 = v0.w - m;
    float d4 = v1.x - m, d5 = v1.y - m, d6 = v1.z - m, d7 = v1.w - m;
    float q = d0*d0 + d1*d1 + d2*d2 + d3*d3 + d4*d4 + d5*d5 + d6*d6 + d7*d7;
    #pragma unroll
    for (int off = 32; off; off >>= 1) q += __shfl_xor(q, off);
    const float r = rsqrtf(q * (1.0f / 512.0f) + 1e-5f);
    const float4 g0 = *(const float4*)(g + (l << 2));
    const float4 g1 = *(const float4*)(g + 256 + (l << 2));
    const float4 b0 = *(const float4*)(bb + (l << 2));
    const float4 b1 = *(const float4*)(bb + 256 + (l << 2));
    float4 o0, o1;
    o0.x = d0 * r * g0.x + b0.x; o0.y = d1 * r * g0.y + b0.y;
    o0.z = d2 * r * g0.z + b0.z; o0.w = d3 * r * g0.w + b0.w;
    o1.x = d4 * r * g1.x + b1.x; o1.y = d5 * r * g1.y + b1.y;
    o1.z = d6 * r * g1.z + b1.z; o1.w = d7 * r * g1.w + b1.w;
    *(float4*)(xr + (l << 2)) = o0;
    *(float4*)(xr + 256 + (l << 2)) = o1;
    *(ushort4*)(xbr + (l << 2)) = make_ushort4(f2h(o0.x), f2h(o0.y), f2h(o0.z), f2h(o0.w));
    *(ushort4*)(xbr + 256 + (l << 2)) = make_ushort4(f2h(o1.x), f2h(o1.y), f2h(o1.z), f2h(o1.w));
}

// ---------------- bilinear warp ----------------------------------------------
__global__ void warp_kernel(const float* __restrict__ x0, const float* __restrict__ shift,
                            const int* __restrict__ pms, float* __restrict__ warped) {
    int idx = blockIdx.x * 256 + threadIdx.x;
    if (idx >= M_ROWS * 512) return;
    int c = idx & 511;
    int m = idx >> 9;
    int t = m % NTOK;
    int b = m / NTOK;
    float max_shift = (float)pms[0];
    float sh = shift[m];
    float flow = sh * max_shift / 256.0f;
    float gx = 2.0f * ((float)c / 511.0f - 0.5f) + flow;
    float ix = ((gx + 1.0f) * 512.0f - 1.0f) * 0.5f;
    ix = fminf(fmaxf(ix, 0.0f), 511.0f);
    float gy = 2.0f * ((float)t / 180.0f - 0.5f);
    float iy = ((gy + 1.0f) * 181.0f - 1.0f) * 0.5f;
    iy = fminf(fmaxf(iy, 0.0f), 180.0f);
    float ix0f = floorf(ix), iy0f = floorf(iy);
    float wx = ix - ix0f, wy = iy - iy0f;
    int ix0 = min(max((int)ix0f, 0), 511);
    int ix1 = min(ix0 + 1, 511);
    int iy0 = min(max((int)iy0f, 0), 180);
    int iy1 = min(iy0 + 1, 180);
    const float* xb = x0 + (size_t)b * NTOK * 512;
    float v00 = xb[iy0 * 512 + ix0], v01 = xb[iy0 * 512 + ix1];
    float v10 = xb[iy1 * 512 + ix0], v11 = xb[iy1 * 512 + ix1];
    warped[idx] = (1.f - wy) * ((1.f - wx) * v00 + wx * v01) + wy * ((1.f - wx) * v10 + wx * v11);
}

extern "C" void kernel_launch(void* const* d_in, const int* in_sizes, int n_in,
                              void* d_out, int out_size, void* d_ws, size_t ws_size,
                              hipStream_t stream) {
    const float* x0   = (const float*)d_in[0];
    const int*   pms  = (const int*)d_in[1];
    const float* pos  = (const float*)d_in[2];
    const float* qkvw = (const float*)d_in[3];
    const float* qkvb = (const float*)d_in[4];
    const float* outw = (const float*)d_in[5];
    const float* outbp= (const float*)d_in[6];
    const float* relp = (const float*)d_in[7];
    const float* rpew = (const float*)d_in[8];
    const float* ln1g = (const float*)d_in[9];
    const float* ln1b = (const float*)d_in[10];
    const float* fw1  = (const float*)d_in[11];
    const float* fb1  = (const float*)d_in[12];
    const float* fw2  = (const float*)d_in[13];
    const float* fb2  = (const float*)d_in[14];
    const float* ln2g = (const float*)d_in[15];
    const float* ln2b = (const float*)d_in[16];
    const float* mw1  = (const float*)d_in[17];
    const float* mb1  = (const float*)d_in[18];
    const float* mw2  = (const float*)d_in[19];
    const float* mb2  = (const float*)d_in[20];

    float* out = (float*)d_out;

    char* ws = (char*)d_ws;
    float*  x     = (float*)ws;                               // 11,862,016 B
    ushort* xb    = (ushort*)(ws + 11862016);                 //  5,931,008 B
    char*   qr    = ws + 11862016 + 5931008;
    ushort* ybuf  = (ushort*)qr;                              // f16 partial 0 (5.9MB)
    ushort* ybuf2 = (ushort*)(qr + 5931008);                  // f16 partial 1 (5.9MB)
    ushort* hbuf  = (ushort*)(qr + 11862016);                 // 23.7MB (ffn hidden)
    ushort* attnb = (ushort*)(qr + 35586048);                 //  5,931,008 B
    float*  rbias = (float*)(qr + 35586048 + 5931008);        //  6*512*4 B
    ushort* wts   = (ushort*)(qr + 35586048 + 5931008 + 12288);
    ushort* qkv_wt = wts;                                     // 6*1536*512
    ushort* out_wt = qkv_wt + 6 * 1536 * 512;                 // 6*512*512
    ushort* f1_wt  = out_wt + 6 * 512 * 512;                  // 6*2048*512
    ushort* f2_wt  = f1_wt  + 6 * 512 * 2048;                 // 6*512*2048
    ushort* w1t    = f2_wt  + 6 * 2048 * 512;                 // 64*512

    hipFuncSetAttribute((const void*)attn_fused,
                        hipFuncAttributeMaxDynamicSharedMemorySize, 124544);

    // single-dispatch weight prep (5 transposes + rbias)
    wt_all<<<4628, 256, 0, stream>>>(qkvw, outw, fw1, fw2, mw1, relp, rpew,
                                     qkv_wt, out_wt, f1_wt, f2_wt, w1t, rbias);

    add_pos_kernel<<<(M_ROWS * 128 + 255) / 256, 256, 0, stream>>>(x0, pos, x, xb);

    const int g_ffn1 = 96 * 16;        // BM=64, N=2048
    const int g_np4  = 96 * 4;         // BM=64, N=512
    for (int i = 0; i < NLAYER; ++i) {
        attn_fused<<<256, 192, 124544, stream>>>(xb, qkv_wt + (size_t)i * 1536 * 512,
                                                 qkvb + i * 1536, rbias + i * 512, attnb);
        mfma_gemm<64, 2, 2><<<g_np4 * 2, 256, 0, stream>>>(attnb, out_wt + (size_t)i * 512 * 512,
                                                           outbp + i * 512, ybuf, M_ROWS, 512, 512);
        lnres_kernel<2><<<1448, 256, 0, stream>>>(x, xb, ybuf, ybuf2, ln1g + i * 512, ln1b + i * 512);
        mfma_gemm<64, 1, 1><<<g_ffn1, 256, 0, stream>>>(xb, f1_wt + (size_t)i * 2048 * 512,
                                                        fb1 + i * 2048, hbuf, M_ROWS, 512, 2048);
        mfma_gemm<64, 2, 2><<<g_np4 * 2, 256, 0, stream>>>(hbuf, f2_wt + (size_t)i * 512 * 2048,
                                                           fb2 + i * 512, ybuf, M_ROWS, 2048, 512);
        lnres_kernel<2><<<1448, 256, 0, stream>>>(x, xb, ybuf, ybuf2, ln2g + i * 512, ln2b + i * 512);
    }

    head_mfma<<<46, 256, 0, stream>>>(xb, w1t, mb1, mw2, mb2, out);
    warp_kernel<<<(M_ROWS * 512 + 255) / 256, 256, 0, stream>>>(x0, out, pms, out + M_ROWS);
}

// Round 15
// 679.116 us; speedup vs baseline: 1.4252x; 1.0690x over previous
//
#include <hip/hip_runtime.h>
#include <hip/hip_bf16.h>
#include <math.h>

#define M_ROWS 5792   // B*N
#define NTOK 181
#define NLAYER 6

typedef __attribute__((ext_vector_type(8))) _Float16 f16x8;
typedef __attribute__((ext_vector_type(4))) float f32x4;
typedef __attribute__((ext_vector_type(16))) float f32x16;

__device__ __forceinline__ ushort f2h(float f) {
    union { _Float16 h; ushort u; } v;
    v.h = (_Float16)f;
    return v.u;
}
__device__ __forceinline__ float h2f(ushort u) {
    union { ushort u; _Float16 h; } v; v.u = u;
    return (float)v.h;
}
__device__ __forceinline__ float gelu_f(float v) {
    return 0.5f * v * (1.0f + erff(v * 0.70710678118654752f));
}
__device__ __forceinline__ void async16(const void* g, void* l) {
    __builtin_amdgcn_global_load_lds((const __attribute__((address_space(1))) void*)g,
                                     (__attribute__((address_space(3))) void*)l, 16, 0, 0);
}

// ---- combined weight prep: 5 transposes (f32 [K][N] -> f16 [N][K]) + rbias ----
__global__ __launch_bounds__(256) void wt_all(const float* __restrict__ qkvw,
                                              const float* __restrict__ outw,
                                              const float* __restrict__ fw1,
                                              const float* __restrict__ fw2,
                                              const float* __restrict__ mw1,
                                              const float* __restrict__ relp,
                                              const float* __restrict__ rpew,
                                              ushort* __restrict__ qkv_wt, ushort* __restrict__ out_wt,
                                              ushort* __restrict__ f1_wt, ushort* __restrict__ f2_wt,
                                              ushort* __restrict__ w1t, float* __restrict__ rbias) {
    int id = blockIdx.x;
    if (id >= 4616) {
        id -= 4616;
        const int l = id >> 1;
        const int j = (id & 1) * 256 + threadIdx.x;
        if (j >= 2 * NTOK - 1) return;
        const float* rp = relp + ((size_t)l * (2 * NTOK - 1) + j) * 64;
        const float* wv = rpew + l * 64;
        float s = 0.f;
        #pragma unroll
        for (int d = 0; d < 64; d += 4) {
            float4 a = *(const float4*)(rp + d);
            float4 b = *(const float4*)(wv + d);
            s += a.x*b.x + a.y*b.y + a.z*b.z + a.w*b.w;
        }
        rbias[l * 512 + j] = s;
        return;
    }
    const float* W; ushort* Wt; int K, N;
    if (id < 1152)      { W = qkvw; Wt = qkv_wt; K = 512;  N = 1536; }
    else if (id < 1536) { W = outw; Wt = out_wt; K = 512;  N = 512;  id -= 1152; }
    else if (id < 3072) { W = fw1;  Wt = f1_wt;  K = 512;  N = 2048; id -= 1536; }
    else if (id < 4608) { W = fw2;  Wt = f2_wt;  K = 2048; N = 512;  id -= 3072; }
    else                { W = mw1;  Wt = w1t;    K = 512;  N = 64;   id -= 4608; }
    const int nk = K >> 6, nn = N >> 6;
    const int per = nk * nn;
    const int z = id / per; id -= z * per;
    const int k0 = (id % nk) * 64, n0 = (id / nk) * 64;

    __shared__ float t[64][65];
    const size_t ls = (size_t)z * K * N;
    const float* Wl = W + ls;
    ushort* Wtl = Wt + ls;
    const int tr = threadIdx.x >> 6, tc = threadIdx.x & 63;
    #pragma unroll
    for (int i = 0; i < 16; ++i) {
        const int r = i * 4 + tr;
        t[r][tc] = Wl[(size_t)(k0 + r) * N + n0 + tc];
    }
    __syncthreads();
    #pragma unroll
    for (int i = 0; i < 16; ++i) {
        const int r = i * 4 + tr;
        Wtl[(size_t)(n0 + r) * K + k0 + tc] = f2h(t[tc][r]);
    }
}

// ---------------- x = x0 + pos_embed (f32 + f16 shadow) ----------------
__global__ void add_pos_kernel(const float* __restrict__ x0, const float* __restrict__ pos,
                               float* __restrict__ x, ushort* __restrict__ xb) {
    int idx = blockIdx.x * 256 + threadIdx.x;
    const int total = M_ROWS * 128;
    if (idx >= total) return;
    int col = idx & 127;
    int m   = idx >> 7;
    int t   = m % NTOK;
    float4 a = ((const float4*)x0)[idx];
    float4 p = ((const float4*)pos)[t * 128 + col];
    a.x += p.x; a.y += p.y; a.z += p.z; a.w += p.w;
    ((float4*)x)[idx] = a;
    ((ushort4*)xb)[idx] = make_ushort4(f2h(a.x), f2h(a.y), f2h(a.z), f2h(a.w));
}

// ---------------- f16 MFMA GEMM: XCD swizzle, optional split-K ----------------
template<int BM, int EPI, int SK>
__global__ __launch_bounds__(256) void mfma_gemm(const ushort* __restrict__ A,
                                                 const ushort* __restrict__ Bt,
                                                 const float* __restrict__ bias,
                                                 void* __restrict__ Cv,
                                                 int M, int K, int N) {
    constexpr int MREP = BM / 32;
    __shared__ __align__(16) ushort sA[2][BM * 32];
    __shared__ __align__(16) ushort sB[2][128 * 32];

    const int NC  = N >> 7;
    const int NR  = (M + BM - 1) / BM;
    const int NRP = (NR + 7) & ~7;
    const int PSB = NRP * NC;
    const int gid = blockIdx.x;
    const int sk  = (SK > 1) ? gid / PSB : 0;
    const int j   = (SK > 1) ? gid % PSB : gid;
    const int r   = (j / (8 * NC)) * 8 + (j & 7);
    const int c   = (j % (8 * NC)) >> 3;
    if (r >= NR) return;

    const int tid = threadIdx.x;
    const int lane = tid & 63;
    const int w = tid >> 6;
    const int wr = w >> 1, wc = w & 1;
    const int row0 = r * BM, col0 = c * 128;
    const int wbase = tid & ~63;

    f32x4 acc[MREP][4];
    const f32x4 zero = {0.f, 0.f, 0.f, 0.f};
    #pragma unroll
    for (int m = 0; m < MREP; ++m)
        #pragma unroll
        for (int n = 0; n < 4; ++n) acc[m][n] = zero;

    auto stage = [&](int buf, int kt) {
        const int k0 = kt << 5;
        #pragma unroll
        for (int i = 0; i < BM / 64; ++i) {
            const int s = i * 256 + tid;
            const int row = s >> 2;
            const int kbl = (s & 3) ^ ((row >> 1) & 3);
            int gr = row0 + row; if (gr > M - 1) gr = M - 1;
            async16(A + (size_t)gr * K + k0 + (kbl << 3),
                    &sA[buf][(i * 256 + wbase) * 8]);
        }
        #pragma unroll
        for (int i = 0; i < 2; ++i) {
            const int s = i * 256 + tid;
            const int nr = s >> 2;
            const int kbl = (s & 3) ^ ((nr >> 1) & 3);
            async16(Bt + (size_t)(col0 + nr) * K + k0 + (kbl << 3),
                    &sB[buf][(i * 256 + wbase) * 8]);
        }
    };

    const int NIT = (K / SK) >> 5;
    const int kt0 = sk * NIT;
    stage(0, kt0);
    const int l15 = lane & 15, kb = lane >> 4;
    for (int it = 0; it < NIT; ++it) {
        __syncthreads();
        if (it + 1 < NIT) stage((it + 1) & 1, kt0 + it + 1);
        const int buf = it & 1;
        f16x8 af[MREP], bfr[4];
        #pragma unroll
        for (int m = 0; m < MREP; ++m) {
            const int rr = wr * (BM / 2) + m * 16 + l15;
            af[m] = *(const f16x8*)&sA[buf][rr * 32 + ((kb ^ ((rr >> 1) & 3)) << 3)];
        }
        #pragma unroll
        for (int n = 0; n < 4; ++n) {
            const int rr = wc * 64 + n * 16 + l15;
            bfr[n] = *(const f16x8*)&sB[buf][rr * 32 + ((kb ^ ((rr >> 1) & 3)) << 3)];
        }
        #pragma unroll
        for (int m = 0; m < MREP; ++m)
            #pragma unroll
            for (int n = 0; n < 4; ++n)
                acc[m][n] = __builtin_amdgcn_mfma_f32_16x16x32_f16(af[m], bfr[n], acc[m][n], 0, 0, 0);
    }

    const int crow = row0 + wr * (BM / 2) + (lane >> 4) * 4;
    const int ccol = col0 + wc * 64 + l15;
    ushort* outh = (ushort*)Cv + (size_t)sk * M * N;
    #pragma unroll
    for (int m = 0; m < MREP; ++m)
        #pragma unroll
        for (int n = 0; n < 4; ++n) {
            const int gc = ccol + n * 16;
            const float bv = (SK == 1 || sk == 0) ? bias[gc] : 0.f;
            #pragma unroll
            for (int rr = 0; rr < 4; ++rr) {
                const int gr = crow + m * 16 + rr;
                if (gr < M) {
                    float v = acc[m][n][rr] + bv;
                    if (EPI == 1)      outh[(size_t)gr * N + gc] = f2h(gelu_f(v));
                    else if (EPI == 2) outh[(size_t)gr * N + gc] = f2h(v);
                    else               ((float*)Cv)[(size_t)gr * N + gc] = v;
                }
            }
        }
}

// ---------------- head MLP via MFMA ------------------------------------------
__global__ __launch_bounds__(256) void head_mfma(const ushort* __restrict__ A,
                                                 const ushort* __restrict__ Bt,
                                                 const float* __restrict__ b1,
                                                 const float* __restrict__ w2,
                                                 const float* __restrict__ b2,
                                                 float* __restrict__ shift) {
    const int M = M_ROWS, K = 512;
    __shared__ __align__(16) ushort sA[2][128 * 32];
    __shared__ __align__(16) ushort sB[2][64 * 32];
    const int tid = threadIdx.x;
    const int lane = tid & 63;
    const int w = tid >> 6;
    const int row0 = blockIdx.x * 128;
    const int wbase = tid & ~63;

    f32x4 acc[2][4];
    const f32x4 zero = {0.f, 0.f, 0.f, 0.f};
    #pragma unroll
    for (int m = 0; m < 2; ++m)
        #pragma unroll
        for (int n = 0; n < 4; ++n) acc[m][n] = zero;

    auto stage = [&](int buf, int kt) {
        const int k0 = kt << 5;
        #pragma unroll
        for (int i = 0; i < 2; ++i) {
            const int s = i * 256 + tid;
            const int row = s >> 2;
            const int kbl = (s & 3) ^ ((row >> 1) & 3);
            int gr = row0 + row; if (gr > M - 1) gr = M - 1;
            async16(A + (size_t)gr * K + k0 + (kbl << 3),
                    &sA[buf][(i * 256 + wbase) * 8]);
        }
        {
            const int s = tid;
            const int nr = s >> 2;
            const int kbl = (s & 3) ^ ((nr >> 1) & 3);
            async16(Bt + (size_t)nr * K + k0 + (kbl << 3),
                    &sB[buf][wbase * 8]);
        }
    };

    stage(0, 0);
    const int l15 = lane & 15, kb = lane >> 4;
    for (int it = 0; it < 16; ++it) {
        __syncthreads();
        if (it + 1 < 16) stage((it + 1) & 1, it + 1);
        const int buf = it & 1;
        f16x8 af[2], bfr[4];
        #pragma unroll
        for (int m = 0; m < 2; ++m) {
            const int r = w * 32 + m * 16 + l15;
            af[m] = *(const f16x8*)&sA[buf][r * 32 + ((kb ^ ((r >> 1) & 3)) << 3)];
        }
        #pragma unroll
        for (int n = 0; n < 4; ++n) {
            const int r = n * 16 + l15;
            bfr[n] = *(const f16x8*)&sB[buf][r * 32 + ((kb ^ ((r >> 1) & 3)) << 3)];
        }
        #pragma unroll
        for (int m = 0; m < 2; ++m)
            #pragma unroll
            for (int n = 0; n < 4; ++n)
                acc[m][n] = __builtin_amdgcn_mfma_f32_16x16x32_f16(af[m], bfr[n], acc[m][n], 0, 0, 0);
    }

    const float b2v = b2[0];
    float b1v[4], w2v[4];
    #pragma unroll
    for (int n = 0; n < 4; ++n) {
        const int c = n * 16 + l15;
        b1v[n] = b1[c];
        w2v[n] = w2[c];
    }
    #pragma unroll
    for (int m = 0; m < 2; ++m) {
        #pragma unroll
        for (int r = 0; r < 4; ++r) {
            float p = 0.f;
            #pragma unroll
            for (int n = 0; n < 4; ++n)
                p += fmaxf(acc[m][n][r] + b1v[n], 0.f) * w2v[n];
            #pragma unroll
            for (int off = 1; off < 16; off <<= 1) p += __shfl_xor(p, off);
            const int gr = row0 + w * 32 + m * 16 + kb * 4 + r;
            if (l15 == 0 && gr < M) shift[gr] = p + b2v;
        }
    }
}

// ============== FUSED qkv-GEMM + attention: one block per (b,h), 6 waves ======
// Phase 1: 192x192x512 GEMM; wave w owns a 32-col slice of qkv output
// (w=0,1: Q; w=2,3: K; w=4,5: V with swapped operands -> vt layout).
// Phase 2: single pass, wave w handles q-rows [32w, 32w+32).
__global__ __launch_bounds__(384, 1) void attn_fused(const ushort* __restrict__ xb,
                                                     const ushort* __restrict__ Wt,
                                                     const float* __restrict__ bias,
                                                     const float* __restrict__ rb,
                                                     ushort* __restrict__ outb) {
    extern __shared__ __align__(16) char smem[];
    ushort* Ks = (ushort*)smem;             // [192][64]
    ushort* Qs = Ks + 12288;                // [192][64]
    ushort* vt = Qs + 12288;                // [64][192]
    ushort* sA = vt + 12288;                // 2 x 192x32
    ushort* sB = sA + 12288;                // 2 x 192x32
    float*  rs = (float*)(smem + 122880);   // 416 floats

    const int b = blockIdx.x >> 3;
    const int h = blockIdx.x & 7;
    const int tid = threadIdx.x, lane = tid & 63, w = tid >> 6;   // w in 0..5
    const int l31 = lane & 31, hi = lane >> 5;
    const int l15 = lane & 15, kb = lane >> 4;
    const int wbase = tid & ~63;

    for (int i = tid; i < 416; i += 384) {
        int j = i - 32;
        rs[i] = (j >= 0 && j < 2 * NTOK - 1) ? rb[j] : 0.f;
    }

    const ushort* Arow = xb + (size_t)(b * NTOK) * 512;

    auto stage = [&](int buf, int it) {
        const int k0 = it << 5;
        #pragma unroll
        for (int i = 0; i < 2; ++i) {
            const int s = i * 384 + tid;            // 768 16B slots for A
            const int row = s >> 2;
            const int kbl = (s & 3) ^ ((row >> 1) & 3);
            const int gr = row < NTOK ? row : NTOK - 1;
            async16(Arow + (size_t)gr * 512 + k0 + (kbl << 3),
                    &sA[buf * 6144 + (i * 384 + wbase) * 8]);
        }
        #pragma unroll
        for (int i = 0; i < 2; ++i) {
            const int s = i * 384 + tid;
            const int n = s >> 2;
            const int kbl = (s & 3) ^ ((n >> 1) & 3);
            const int wrow = (n >> 6) * 512 + h * 64 + (n & 63);
            async16(Wt + (size_t)wrow * 512 + k0 + (kbl << 3),
                    &sB[buf * 6144 + (i * 384 + wbase) * 8]);
        }
    };

    // -------- phase 1: GEMM, 24 acc tiles per wave --------
    f32x4 acc[24];
    const f32x4 zero = {0.f, 0.f, 0.f, 0.f};
    #pragma unroll
    for (int t = 0; t < 24; ++t) acc[t] = zero;

    const int cb = (w < 4) ? ((w >> 1) * 64 + (w & 1) * 32)   // 0,32,64,96
                           : (128 + (w - 4) * 32);            // 128,160

    stage(0, 0);
    for (int it = 0; it < 16; ++it) {
        __syncthreads();
        if (it + 1 < 16) stage((it + 1) & 1, it + 1);
        const ushort* a  = &sA[(it & 1) * 6144];
        const ushort* bw = &sB[(it & 1) * 6144];
        if (w < 4) {                 // Q/K: D[token][col], 12 Mtiles x 2 Ntiles
            f16x8 af[12], bf[2];
            #pragma unroll
            for (int mt = 0; mt < 12; ++mt) {
                const int r = mt * 16 + l15;
                af[mt] = *(const f16x8*)&a[r * 32 + ((kb ^ ((r >> 1) & 3)) << 3)];
            }
            #pragma unroll
            for (int nt = 0; nt < 2; ++nt) {
                const int n = cb + nt * 16 + l15;
                bf[nt] = *(const f16x8*)&bw[n * 32 + ((kb ^ ((n >> 1) & 3)) << 3)];
            }
            #pragma unroll
            for (int mt = 0; mt < 12; ++mt)
                #pragma unroll
                for (int nt = 0; nt < 2; ++nt)
                    acc[mt * 2 + nt] = __builtin_amdgcn_mfma_f32_16x16x32_f16(af[mt], bf[nt], acc[mt * 2 + nt], 0, 0, 0);
        } else {                     // V: D[col][token], 2 Mtiles x 12 Ntiles
            f16x8 af[2], bf[12];
            #pragma unroll
            for (int mt = 0; mt < 2; ++mt) {
                const int n = cb + mt * 16 + l15;
                af[mt] = *(const f16x8*)&bw[n * 32 + ((kb ^ ((n >> 1) & 3)) << 3)];
            }
            #pragma unroll
            for (int nt = 0; nt < 12; ++nt) {
                const int r = nt * 16 + l15;
                bf[nt] = *(const f16x8*)&a[r * 32 + ((kb ^ ((r >> 1) & 3)) << 3)];
            }
            #pragma unroll
            for (int mt = 0; mt < 2; ++mt)
                #pragma unroll
                for (int nt = 0; nt < 12; ++nt)
                    acc[mt * 12 + nt] = __builtin_amdgcn_mfma_f32_16x16x32_f16(af[mt], bf[nt], acc[mt * 12 + nt], 0, 0, 0);
        }
    }

    // epilogue: bias + write to attn LDS layouts (16x16 C/D: row=kb*4+r, col=l15)
    if (w < 4) {
        ushort* dst = (w < 2) ? Qs : Ks;
        const int dbase = (w & 1) * 32;                 // col within 64-d head slice
        const int boff = (w < 2 ? 0 : 512) + h * 64;
        #pragma unroll
        for (int nt = 0; nt < 2; ++nt) {
            const int d = dbase + nt * 16 + l15;
            const float bv = bias[boff + d];
            #pragma unroll
            for (int mt = 0; mt < 12; ++mt)
                #pragma unroll
                for (int r = 0; r < 4; ++r) {
                    const int tok = mt * 16 + kb * 4 + r;
                    dst[tok * 64 + (((d >> 3) ^ (tok & 7)) << 3) + (d & 7)] =
                        f2h(acc[mt * 2 + nt][r] + bv);
                }
        }
    } else {
        const int dbase = (w - 4) * 32;
        #pragma unroll
        for (int mt = 0; mt < 2; ++mt)
            #pragma unroll
            for (int r = 0; r < 4; ++r) {
                const int d = dbase + mt * 16 + kb * 4 + r;
                const float bv = bias[1024 + h * 64 + d];
                const int sd = (d ^ (d >> 3)) & 7;
                #pragma unroll
                for (int nt = 0; nt < 12; ++nt) {
                    const int tok = nt * 16 + l15;
                    vt[d * 192 + (((tok >> 3) ^ sd) << 3) + (tok & 7)] =
                        f2h(acc[mt * 12 + nt][r] + bv);
                }
            }
    }
    __syncthreads();

    // -------- phase 2: attention, wave w handles q in [32w, 32w+32) --------
    {
        const int q0 = w * 32;
        const int q = q0 + l31;
        f16x8 qf[4];
        #pragma unroll
        for (int ds = 0; ds < 4; ++ds)
            qf[ds] = *(const f16x8*)&Qs[q * 64 + (((2 * ds + hi) ^ (q & 7)) << 3)];

        f32x16 S[6];
        #pragma unroll
        for (int kt = 0; kt < 6; ++kt)
            #pragma unroll
            for (int r = 0; r < 16; ++r) S[kt][r] = 0.f;
        __builtin_amdgcn_s_setprio(1);
        #pragma unroll
        for (int kt = 0; kt < 6; ++kt) {
            const int krow = kt * 32 + l31;
            #pragma unroll
            for (int ds = 0; ds < 4; ++ds) {
                f16x8 kf = *(const f16x8*)&Ks[krow * 64 + (((2 * ds + hi) ^ (krow & 7)) << 3)];
                S[kt] = __builtin_amdgcn_mfma_f32_32x32x16_f16(kf, qf[ds], S[kt], 0, 0, 0);
            }
        }
        __builtin_amdgcn_s_setprio(0);

        float mx = -1e30f;
        #pragma unroll
        for (int kt = 0; kt < 6; ++kt)
            #pragma unroll
            for (int r = 0; r < 16; ++r) {
                const int k = kt * 32 + (r & 3) + 8 * (r >> 2) + 4 * hi;
                float s = (k < NTOK) ? S[kt][r] * 0.125f + rs[k - q + 212] : -1e30f;
                S[kt][r] = s;
                mx = fmaxf(mx, s);
            }
        mx = fmaxf(mx, __shfl_xor(mx, 32));
        float sum = 0.f;
        #pragma unroll
        for (int kt = 0; kt < 6; ++kt)
            #pragma unroll
            for (int r = 0; r < 16; ++r) {
                float e = __expf(S[kt][r] - mx);
                S[kt][r] = e;
                sum += e;
            }
        sum += __shfl_xor(sum, 32);
        const float inv = 1.0f / sum;
        #pragma unroll
        for (int kt = 0; kt < 6; ++kt)
            #pragma unroll
            for (int r = 0; r < 16; ++r) S[kt][r] *= inv;

        f32x16 O[2];
        #pragma unroll
        for (int nt = 0; nt < 2; ++nt)
            #pragma unroll
            for (int r = 0; r < 16; ++r) O[nt][r] = 0.f;
        #pragma unroll
        for (int kt2 = 0; kt2 < 12; ++kt2) {
            const int kt = kt2 >> 1, half = kt2 & 1;
            uint p[4];
            #pragma unroll
            for (int m = 0; m < 4; ++m)
                p[m] = (uint)f2h(S[kt][8 * half + 2 * m]) |
                       ((uint)f2h(S[kt][8 * half + 2 * m + 1]) << 16);
            const uint s0l = (uint)__shfl_xor((int)p[0], 32);
            const uint s0h = (uint)__shfl_xor((int)p[1], 32);
            const uint s1l = (uint)__shfl_xor((int)p[2], 32);
            const uint s1h = (uint)__shfl_xor((int)p[3], 32);
            uint fa[4];
            if (hi == 0) { fa[0] = p[0]; fa[1] = p[1]; fa[2] = s0l; fa[3] = s0h; }
            else         { fa[0] = s1l; fa[1] = s1h; fa[2] = p[2]; fa[3] = p[3]; }
            const f16x8 pa = *(const f16x8*)fa;
            __builtin_amdgcn_s_setprio(1);
            #pragma unroll
            for (int nt = 0; nt < 2; ++nt) {
                const int d = nt * 32 + l31;
                f16x8 vf = *(const f16x8*)&vt[d * 192 + (((2 * kt2 + hi) ^ ((d ^ (d >> 3)) & 7)) << 3)];
                O[nt] = __builtin_amdgcn_mfma_f32_32x32x16_f16(pa, vf, O[nt], 0, 0, 0);
            }
            __builtin_amdgcn_s_setprio(0);
        }

        #pragma unroll
        for (int nt = 0; nt < 2; ++nt)
            #pragma unroll
            for (int r = 0; r < 16; ++r) {
                const int qr = q0 + (r & 3) + 8 * (r >> 2) + 4 * hi;
                if (qr < NTOK)
                    outb[(size_t)(b * NTOK + qr) * 512 + h * 64 + nt * 32 + l31] = f2h(O[nt][r]);
            }
    }
}

// ---------------- x = LayerNorm(x + y0 + y1) * g + b ; writes f32 x, f16 xb ----
template<int NY>
__global__ __launch_bounds__(256) void lnres_kernel(float* __restrict__ x, ushort* __restrict__ xb,
                                                    const ushort* __restrict__ y,
                                                    const ushort* __restrict__ y1,
                                                    const float* __restrict__ g, const float* __restrict__ bb) {
    const int row = blockIdx.x * 4 + (threadIdx.x >> 6);
    const int l = threadIdx.x & 63;
    float* xr = x + (size_t)row * 512;
    ushort* xbr = xb + (size_t)row * 512;
    const ushort* yr = y + (size_t)row * 512;
    float4 v0 = *(const float4*)(xr + (l << 2));
    float4 v1 = *(const float4*)(xr + 256 + (l << 2));
    const ushort4 u0 = *(const ushort4*)(yr + (l << 2));
    const ushort4 u1 = *(const ushort4*)(yr + 256 + (l << 2));
    v0.x += h2f(u0.x); v0.y += h2f(u0.y); v0.z += h2f(u0.z); v0.w += h2f(u0.w);
    v1.x += h2f(u1.x); v1.y += h2f(u1.y); v1.z += h2f(u1.z); v1.w += h2f(u1.w);
    if (NY == 2) {
        const ushort* y1r = y1 + (size_t)row * 512;
        const ushort4 w0 = *(const ushort4*)(y1r + (l << 2));
        const ushort4 w1 = *(const ushort4*)(y1r + 256 + (l << 2));
        v0.x += h2f(w0.x); v0.y += h2f(w0.y); v0.z += h2f(w0.z); v0.w += h2f(w0.w);
        v1.x += h2f(w1.x); v1.y += h2f(w1.y); v1.z += h2f(w1.z); v1.w += h2f(w1.w);
    }
    float s = v0.x + v0.y + v0.z + v0.w + v1.x + v1.y + v1.z + v1.w;
    #pragma unroll
    for (int off = 32; off; off >>= 1) s += __shfl_xor(s, off);
    const float m = s * (1.0f / 512.0f);
    float d0 = v0.x - m, d1 = v0.y - m, d2 = v0.z - m, d3 = v0.w - m;
    float d4 = v1.x - m, d5 = v1.y - m, d6 = v1.z - m, d7 = v1.w - m;
    float q = d0*d0 + d1*d1 + d2*d2 + d3*d3 + d4*d4 + d5*d5 + d6*d6 + d7*d7;
    #pragma unroll
    for (int off = 32; off; off >>= 1) q += __shfl_xor(q, off);
    const float r = rsqrtf(q * (1.0f / 512.0f) + 1e-5f);
    const float4 g0 = *(const float4*)(g + (l << 2));
    const float4 g1 = *(const float4*)(g + 256 + (l << 2));
    const float4 b0 = *(const float4*)(bb + (l << 2));
    const float4 b1 = *(const float4*)(bb + 256 + (l << 2));
    float4 o0, o1;
    o0.x = d0 * r * g0.x + b0.x; o0.y = d1 * r * g0.y + b0.y;
    o0.z = d2 * r * g0.z + b0.z; o0.w = d3 * r * g0.w + b0.w;
    o1.x = d4 * r * g1.x + b1.x; o1.y = d5 * r * g1.y + b1.y;
    o1.z = d6 * r * g1.z + b1.z; o1.w = d7 * r * g1.w + b1.w;
    *(float4*)(xr + (l << 2)) = o0;
    *(float4*)(xr + 256 + (l << 2)) = o1;
    *(ushort4*)(xbr + (l << 2)) = make_ushort4(f2h(o0.x), f2h(o0.y), f2h(o0.z), f2h(o0.w));
    *(ushort4*)(xbr + 256 + (l << 2)) = make_ushort4(f2h(o1.x), f2h(o1.y), f2h(o1.z), f2h(o1.w));
}

// ---------------- bilinear warp ----------------------------------------------
__global__ void warp_kernel(const float* __restrict__ x0, const float* __restrict__ shift,
                            const int* __restrict__ pms, float* __restrict__ warped) {
    int idx = blockIdx.x * 256 + threadIdx.x;
    if (idx >= M_ROWS * 512) return;
    int c = idx & 511;
    int m = idx >> 9;
    int t = m % NTOK;
    int b = m / NTOK;
    float max_shift = (float)pms[0];
    float sh = shift[m];
    float flow = sh * max_shift / 256.0f;
    float gx = 2.0f * ((float)c / 511.0f - 0.5f) + flow;
    float ix = ((gx + 1.0f) * 512.0f - 1.0f) * 0.5f;
    ix = fminf(fmaxf(ix, 0.0f), 511.0f);
    float gy = 2.0f * ((float)t / 180.0f - 0.5f);
    float iy = ((gy + 1.0f) * 181.0f - 1.0f) * 0.5f;
    iy = fminf(fmaxf(iy, 0.0f), 180.0f);
    float ix0f = floorf(ix), iy0f = floorf(iy);
    float wx = ix - ix0f, wy = iy - iy0f;
    int ix0 = min(max((int)ix0f, 0), 511);
    int ix1 = min(ix0 + 1, 511);
    int iy0 = min(max((int)iy0f, 0), 180);
    int iy1 = min(iy0 + 1, 180);
    const float* xb = x0 + (size_t)b * NTOK * 512;
    float v00 = xb[iy0 * 512 + ix0], v01 = xb[iy0 * 512 + ix1];
    float v10 = xb[iy1 * 512 + ix0], v11 = xb[iy1 * 512 + ix1];
    warped[idx] = (1.f - wy) * ((1.f - wx) * v00 + wx * v01) + wy * ((1.f - wx) * v10 + wx * v11);
}

extern "C" void kernel_launch(void* const* d_in, const int* in_sizes, int n_in,
                              void* d_out, int out_size, void* d_ws, size_t ws_size,
                              hipStream_t stream) {
    const float* x0   = (const float*)d_in[0];
    const int*   pms  = (const int*)d_in[1];
    const float* pos  = (const float*)d_in[2];
    const float* qkvw = (const float*)d_in[3];
    const float* qkvb = (const float*)d_in[4];
    const float* outw = (const float*)d_in[5];
    const float* outbp= (const float*)d_in[6];
    const float* relp = (const float*)d_in[7];
    const float* rpew = (const float*)d_in[8];
    const float* ln1g = (const float*)d_in[9];
    const float* ln1b = (const float*)d_in[10];
    const float* fw1  = (const float*)d_in[11];
    const float* fb1  = (const float*)d_in[12];
    const float* fw2  = (const float*)d_in[13];
    const float* fb2  = (const float*)d_in[14];
    const float* ln2g = (const float*)d_in[15];
    const float* ln2b = (const float*)d_in[16];
    const float* mw1  = (const float*)d_in[17];
    const float* mb1  = (const float*)d_in[18];
    const float* mw2  = (const float*)d_in[19];
    const float* mb2  = (const float*)d_in[20];

    float* out = (float*)d_out;

    char* ws = (char*)d_ws;
    float*  x     = (float*)ws;                               // 11,862,016 B
    ushort* xb    = (ushort*)(ws + 11862016);                 //  5,931,008 B
    char*   qr    = ws + 11862016 + 5931008;
    ushort* ybuf  = (ushort*)qr;                              // f16 partial 0 (5.9MB)
    ushort* ybuf2 = (ushort*)(qr + 5931008);                  // f16 partial 1 (5.9MB)
    ushort* hbuf  = (ushort*)(qr + 11862016);                 // 23.7MB (ffn hidden)
    ushort* attnb = (ushort*)(qr + 35586048);                 //  5,931,008 B
    float*  rbias = (float*)(qr + 35586048 + 5931008);        //  6*512*4 B
    ushort* wts   = (ushort*)(qr + 35586048 + 5931008 + 12288);
    ushort* qkv_wt = wts;                                     // 6*1536*512
    ushort* out_wt = qkv_wt + 6 * 1536 * 512;                 // 6*512*512
    ushort* f1_wt  = out_wt + 6 * 512 * 512;                  // 6*2048*512
    ushort* f2_wt  = f1_wt  + 6 * 512 * 2048;                 // 6*512*2048
    ushort* w1t    = f2_wt  + 6 * 2048 * 512;                 // 64*512

    hipFuncSetAttribute((const void*)attn_fused,
                        hipFuncAttributeMaxDynamicSharedMemorySize, 124544);

    // single-dispatch weight prep (5 transposes + rbias)
    wt_all<<<4628, 256, 0, stream>>>(qkvw, outw, fw1, fw2, mw1, relp, rpew,
                                     qkv_wt, out_wt, f1_wt, f2_wt, w1t, rbias);

    add_pos_kernel<<<(M_ROWS * 128 + 255) / 256, 256, 0, stream>>>(x0, pos, x, xb);

    const int g_ffn1 = 96 * 16;        // BM=64, N=2048
    const int g_np4  = 96 * 4;         // BM=64, N=512
    for (int i = 0; i < NLAYER; ++i) {
        attn_fused<<<256, 384, 124544, stream>>>(xb, qkv_wt + (size_t)i * 1536 * 512,
                                                 qkvb + i * 1536, rbias + i * 512, attnb);
        mfma_gemm<64, 2, 2><<<g_np4 * 2, 256, 0, stream>>>(attnb, out_wt + (size_t)i * 512 * 512,
                                                           outbp + i * 512, ybuf, M_ROWS, 512, 512);
        lnres_kernel<2><<<1448, 256, 0, stream>>>(x, xb, ybuf, ybuf2, ln1g + i * 512, ln1b + i * 512);
        mfma_gemm<64, 1, 1><<<g_ffn1, 256, 0, stream>>>(xb, f1_wt + (size_t)i * 2048 * 512,
                                                        fb1 + i * 2048, hbuf, M_ROWS, 512, 2048);
        mfma_gemm<64, 2, 2><<<g_np4 * 2, 256, 0, stream>>>(hbuf, f2_wt + (size_t)i * 512 * 2048,
                                                           fb2 + i * 512, ybuf, M_ROWS, 2048, 512);
        lnres_kernel<2><<<1448, 256, 0, stream>>>(x, xb, ybuf, ybuf2, ln2g + i * 512, ln2b + i * 512);
    }

    head_mfma<<<46, 256, 0, stream>>>(xb, w1t, mb1, mw2, mb2, out);
    warp_kernel<<<(M_ROWS * 512 + 255) / 256, 256, 0, stream>>>(x0, out, pms, out + M_ROWS);
}

// Round 16
// 650.109 us; speedup vs baseline: 1.4888x; 1.0446x over previous
//
#include <hip/hip_runtime.h>
#include <hip/hip_bf16.h>
#include <math.h>

#define M_ROWS 5792   // B*N
#define NTOK 181
#define NLAYER 6

typedef __attribute__((ext_vector_type(8))) _Float16 f16x8;
typedef __attribute__((ext_vector_type(4))) float f32x4;
typedef __attribute__((ext_vector_type(16))) float f32x16;

__device__ __forceinline__ ushort f2h(float f) {
    union { _Float16 h; ushort u; } v;
    v.h = (_Float16)f;
    return v.u;
}
__device__ __forceinline__ float h2f(ushort u) {
    union { ushort u; _Float16 h; } v; v.u = u;
    return (float)v.h;
}
__device__ __forceinline__ float gelu_f(float v) {
    return 0.5f * v * (1.0f + erff(v * 0.70710678118654752f));
}
__device__ __forceinline__ void async16(const void* g, void* l) {
    __builtin_amdgcn_global_load_lds((const __attribute__((address_space(1))) void*)g,
                                     (__attribute__((address_space(3))) void*)l, 16, 0, 0);
}

// ---- combined prologue: 5 weight transposes + rbias + add_pos ----------------
// blocks [0,4608) transposes | [4608,4616) mlp_w1 | [4616,4628) rbias |
// [4628,7524) add_pos (x0+pos -> xb f16)
__global__ __launch_bounds__(256) void wt_all(const float* __restrict__ qkvw,
                                              const float* __restrict__ outw,
                                              const float* __restrict__ fw1,
                                              const float* __restrict__ fw2,
                                              const float* __restrict__ mw1,
                                              const float* __restrict__ relp,
                                              const float* __restrict__ rpew,
                                              const float* __restrict__ x0,
                                              const float* __restrict__ pos,
                                              ushort* __restrict__ qkv_wt, ushort* __restrict__ out_wt,
                                              ushort* __restrict__ f1_wt, ushort* __restrict__ f2_wt,
                                              ushort* __restrict__ w1t, float* __restrict__ rbias,
                                              ushort* __restrict__ xb) {
    int id = blockIdx.x;
    if (id >= 4628) {                      // add_pos
        const int idx = (id - 4628) * 256 + threadIdx.x;   // float4 index
        if (idx >= M_ROWS * 128) return;
        const int col = idx & 127;
        const int m   = idx >> 7;
        const int t   = m % NTOK;
        float4 a = ((const float4*)x0)[idx];
        float4 p = ((const float4*)pos)[t * 128 + col];
        a.x += p.x; a.y += p.y; a.z += p.z; a.w += p.w;
        ((ushort4*)xb)[idx] = make_ushort4(f2h(a.x), f2h(a.y), f2h(a.z), f2h(a.w));
        return;
    }
    if (id >= 4616) {                      // rbias
        id -= 4616;
        const int l = id >> 1;
        const int j = (id & 1) * 256 + threadIdx.x;
        if (j >= 2 * NTOK - 1) return;
        const float* rp = relp + ((size_t)l * (2 * NTOK - 1) + j) * 64;
        const float* wv = rpew + l * 64;
        float s = 0.f;
        #pragma unroll
        for (int d = 0; d < 64; d += 4) {
            float4 a = *(const float4*)(rp + d);
            float4 b = *(const float4*)(wv + d);
            s += a.x*b.x + a.y*b.y + a.z*b.z + a.w*b.w;
        }
        rbias[l * 512 + j] = s;
        return;
    }
    const float* W; ushort* Wt; int K, N;
    if (id < 1152)      { W = qkvw; Wt = qkv_wt; K = 512;  N = 1536; }
    else if (id < 1536) { W = outw; Wt = out_wt; K = 512;  N = 512;  id -= 1152; }
    else if (id < 3072) { W = fw1;  Wt = f1_wt;  K = 512;  N = 2048; id -= 1536; }
    else if (id < 4608) { W = fw2;  Wt = f2_wt;  K = 2048; N = 512;  id -= 3072; }
    else                { W = mw1;  Wt = w1t;    K = 512;  N = 64;   id -= 4608; }
    const int nk = K >> 6, nn = N >> 6;
    const int per = nk * nn;
    const int z = id / per; id -= z * per;
    const int k0 = (id % nk) * 64, n0 = (id / nk) * 64;

    __shared__ float t[64][65];
    const size_t ls = (size_t)z * K * N;
    const float* Wl = W + ls;
    ushort* Wtl = Wt + ls;
    const int tr = threadIdx.x >> 6, tc = threadIdx.x & 63;
    #pragma unroll
    for (int i = 0; i < 16; ++i) {
        const int r = i * 4 + tr;
        t[r][tc] = Wl[(size_t)(k0 + r) * N + n0 + tc];
    }
    __syncthreads();
    #pragma unroll
    for (int i = 0; i < 16; ++i) {
        const int r = i * 4 + tr;
        Wtl[(size_t)(n0 + r) * K + k0 + tc] = f2h(t[tc][r]);
    }
}

// ---------------- f16 MFMA GEMM: XCD swizzle, optional split-K ----------------
template<int BM, int EPI, int SK>
__global__ __launch_bounds__(256) void mfma_gemm(const ushort* __restrict__ A,
                                                 const ushort* __restrict__ Bt,
                                                 const float* __restrict__ bias,
                                                 void* __restrict__ Cv,
                                                 int M, int K, int N) {
    constexpr int MREP = BM / 32;
    __shared__ __align__(16) ushort sA[2][BM * 32];
    __shared__ __align__(16) ushort sB[2][128 * 32];

    const int NC  = N >> 7;
    const int NR  = (M + BM - 1) / BM;
    const int NRP = (NR + 7) & ~7;
    const int PSB = NRP * NC;
    const int gid = blockIdx.x;
    const int sk  = (SK > 1) ? gid / PSB : 0;
    const int j   = (SK > 1) ? gid % PSB : gid;
    const int r   = (j / (8 * NC)) * 8 + (j & 7);
    const int c   = (j % (8 * NC)) >> 3;
    if (r >= NR) return;

    const int tid = threadIdx.x;
    const int lane = tid & 63;
    const int w = tid >> 6;
    const int wr = w >> 1, wc = w & 1;
    const int row0 = r * BM, col0 = c * 128;
    const int wbase = tid & ~63;

    f32x4 acc[MREP][4];
    const f32x4 zero = {0.f, 0.f, 0.f, 0.f};
    #pragma unroll
    for (int m = 0; m < MREP; ++m)
        #pragma unroll
        for (int n = 0; n < 4; ++n) acc[m][n] = zero;

    auto stage = [&](int buf, int kt) {
        const int k0 = kt << 5;
        #pragma unroll
        for (int i = 0; i < BM / 64; ++i) {
            const int s = i * 256 + tid;
            const int row = s >> 2;
            const int kbl = (s & 3) ^ ((row >> 1) & 3);
            int gr = row0 + row; if (gr > M - 1) gr = M - 1;
            async16(A + (size_t)gr * K + k0 + (kbl << 3),
                    &sA[buf][(i * 256 + wbase) * 8]);
        }
        #pragma unroll
        for (int i = 0; i < 2; ++i) {
            const int s = i * 256 + tid;
            const int nr = s >> 2;
            const int kbl = (s & 3) ^ ((nr >> 1) & 3);
            async16(Bt + (size_t)(col0 + nr) * K + k0 + (kbl << 3),
                    &sB[buf][(i * 256 + wbase) * 8]);
        }
    };

    const int NIT = (K / SK) >> 5;
    const int kt0 = sk * NIT;
    stage(0, kt0);
    const int l15 = lane & 15, kb = lane >> 4;
    for (int it = 0; it < NIT; ++it) {
        __syncthreads();
        if (it + 1 < NIT) stage((it + 1) & 1, kt0 + it + 1);
        const int buf = it & 1;
        f16x8 af[MREP], bfr[4];
        #pragma unroll
        for (int m = 0; m < MREP; ++m) {
            const int rr = wr * (BM / 2) + m * 16 + l15;
            af[m] = *(const f16x8*)&sA[buf][rr * 32 + ((kb ^ ((rr >> 1) & 3)) << 3)];
        }
        #pragma unroll
        for (int n = 0; n < 4; ++n) {
            const int rr = wc * 64 + n * 16 + l15;
            bfr[n] = *(const f16x8*)&sB[buf][rr * 32 + ((kb ^ ((rr >> 1) & 3)) << 3)];
        }
        #pragma unroll
        for (int m = 0; m < MREP; ++m)
            #pragma unroll
            for (int n = 0; n < 4; ++n)
                acc[m][n] = __builtin_amdgcn_mfma_f32_16x16x32_f16(af[m], bfr[n], acc[m][n], 0, 0, 0);
    }

    const int crow = row0 + wr * (BM / 2) + (lane >> 4) * 4;
    const int ccol = col0 + wc * 64 + l15;
    ushort* outh = (ushort*)Cv + (size_t)sk * M * N;
    #pragma unroll
    for (int m = 0; m < MREP; ++m)
        #pragma unroll
        for (int n = 0; n < 4; ++n) {
            const int gc = ccol + n * 16;
            const float bv = (SK == 1 || sk == 0) ? bias[gc] : 0.f;
            #pragma unroll
            for (int rr = 0; rr < 4; ++rr) {
                const int gr = crow + m * 16 + rr;
                if (gr < M) {
                    float v = acc[m][n][rr] + bv;
                    if (EPI == 1)      outh[(size_t)gr * N + gc] = f2h(gelu_f(v));
                    else if (EPI == 2) outh[(size_t)gr * N + gc] = f2h(v);
                    else               ((float*)Cv)[(size_t)gr * N + gc] = v;
                }
            }
        }
}

// ---------------- head MLP via MFMA ------------------------------------------
__global__ __launch_bounds__(256) void head_mfma(const ushort* __restrict__ A,
                                                 const ushort* __restrict__ Bt,
                                                 const float* __restrict__ b1,
                                                 const float* __restrict__ w2,
                                                 const float* __restrict__ b2,
                                                 float* __restrict__ shift) {
    const int M = M_ROWS, K = 512;
    __shared__ __align__(16) ushort sA[2][128 * 32];
    __shared__ __align__(16) ushort sB[2][64 * 32];
    const int tid = threadIdx.x;
    const int lane = tid & 63;
    const int w = tid >> 6;
    const int row0 = blockIdx.x * 128;
    const int wbase = tid & ~63;

    f32x4 acc[2][4];
    const f32x4 zero = {0.f, 0.f, 0.f, 0.f};
    #pragma unroll
    for (int m = 0; m < 2; ++m)
        #pragma unroll
        for (int n = 0; n < 4; ++n) acc[m][n] = zero;

    auto stage = [&](int buf, int kt) {
        const int k0 = kt << 5;
        #pragma unroll
        for (int i = 0; i < 2; ++i) {
            const int s = i * 256 + tid;
            const int row = s >> 2;
            const int kbl = (s & 3) ^ ((row >> 1) & 3);
            int gr = row0 + row; if (gr > M - 1) gr = M - 1;
            async16(A + (size_t)gr * K + k0 + (kbl << 3),
                    &sA[buf][(i * 256 + wbase) * 8]);
        }
        {
            const int s = tid;
            const int nr = s >> 2;
            const int kbl = (s & 3) ^ ((nr >> 1) & 3);
            async16(Bt + (size_t)nr * K + k0 + (kbl << 3),
                    &sB[buf][wbase * 8]);
        }
    };

    stage(0, 0);
    const int l15 = lane & 15, kb = lane >> 4;
    for (int it = 0; it < 16; ++it) {
        __syncthreads();
        if (it + 1 < 16) stage((it + 1) & 1, it + 1);
        const int buf = it & 1;
        f16x8 af[2], bfr[4];
        #pragma unroll
        for (int m = 0; m < 2; ++m) {
            const int r = w * 32 + m * 16 + l15;
            af[m] = *(const f16x8*)&sA[buf][r * 32 + ((kb ^ ((r >> 1) & 3)) << 3)];
        }
        #pragma unroll
        for (int n = 0; n < 4; ++n) {
            const int r = n * 16 + l15;
            bfr[n] = *(const f16x8*)&sB[buf][r * 32 + ((kb ^ ((r >> 1) & 3)) << 3)];
        }
        #pragma unroll
        for (int m = 0; m < 2; ++m)
            #pragma unroll
            for (int n = 0; n < 4; ++n)
                acc[m][n] = __builtin_amdgcn_mfma_f32_16x16x32_f16(af[m], bfr[n], acc[m][n], 0, 0, 0);
    }

    const float b2v = b2[0];
    float b1v[4], w2v[4];
    #pragma unroll
    for (int n = 0; n < 4; ++n) {
        const int c = n * 16 + l15;
        b1v[n] = b1[c];
        w2v[n] = w2[c];
    }
    #pragma unroll
    for (int m = 0; m < 2; ++m) {
        #pragma unroll
        for (int r = 0; r < 4; ++r) {
            float p = 0.f;
            #pragma unroll
            for (int n = 0; n < 4; ++n)
                p += fmaxf(acc[m][n][r] + b1v[n], 0.f) * w2v[n];
            #pragma unroll
            for (int off = 1; off < 16; off <<= 1) p += __shfl_xor(p, off);
            const int gr = row0 + w * 32 + m * 16 + kb * 4 + r;
            if (l15 == 0 && gr < M) shift[gr] = p + b2v;
        }
    }
}

// ============== FUSED qkv-GEMM + attention: one block per (b,h), 6 waves ======
__global__ __launch_bounds__(384, 1) void attn_fused(const ushort* __restrict__ xb,
                                                     const ushort* __restrict__ Wt,
                                                     const float* __restrict__ bias,
                                                     const float* __restrict__ rb,
                                                     ushort* __restrict__ outb) {
    extern __shared__ __align__(16) char smem[];
    ushort* Ks = (ushort*)smem;             // [192][64]
    ushort* Qs = Ks + 12288;                // [192][64]
    ushort* vt = Qs + 12288;                // [64][192]
    ushort* sA = vt + 12288;                // 2 x 192x32
    ushort* sB = sA + 12288;                // 2 x 192x32
    float*  rs = (float*)(smem + 122880);   // 416 floats

    const int b = blockIdx.x >> 3;
    const int h = blockIdx.x & 7;
    const int tid = threadIdx.x, lane = tid & 63, w = tid >> 6;   // w in 0..5
    const int l31 = lane & 31, hi = lane >> 5;
    const int l15 = lane & 15, kb = lane >> 4;
    const int wbase = tid & ~63;

    for (int i = tid; i < 416; i += 384) {
        int j = i - 32;
        rs[i] = (j >= 0 && j < 2 * NTOK - 1) ? rb[j] : 0.f;
    }

    const ushort* Arow = xb + (size_t)(b * NTOK) * 512;

    auto stage = [&](int buf, int it) {
        const int k0 = it << 5;
        #pragma unroll
        for (int i = 0; i < 2; ++i) {
            const int s = i * 384 + tid;
            const int row = s >> 2;
            const int kbl = (s & 3) ^ ((row >> 1) & 3);
            const int gr = row < NTOK ? row : NTOK - 1;
            async16(Arow + (size_t)gr * 512 + k0 + (kbl << 3),
                    &sA[buf * 6144 + (i * 384 + wbase) * 8]);
        }
        #pragma unroll
        for (int i = 0; i < 2; ++i) {
            const int s = i * 384 + tid;
            const int n = s >> 2;
            const int kbl = (s & 3) ^ ((n >> 1) & 3);
            const int wrow = (n >> 6) * 512 + h * 64 + (n & 63);
            async16(Wt + (size_t)wrow * 512 + k0 + (kbl << 3),
                    &sB[buf * 6144 + (i * 384 + wbase) * 8]);
        }
    };

    // -------- phase 1: GEMM, 24 acc tiles per wave --------
    f32x4 acc[24];
    const f32x4 zero = {0.f, 0.f, 0.f, 0.f};
    #pragma unroll
    for (int t = 0; t < 24; ++t) acc[t] = zero;

    const int cb = (w < 4) ? ((w >> 1) * 64 + (w & 1) * 32)
                           : (128 + (w - 4) * 32);

    stage(0, 0);
    for (int it = 0; it < 16; ++it) {
        __syncthreads();
        if (it + 1 < 16) stage((it + 1) & 1, it + 1);
        const ushort* a  = &sA[(it & 1) * 6144];
        const ushort* bw = &sB[(it & 1) * 6144];
        if (w < 4) {
            f16x8 af[12], bf[2];
            #pragma unroll
            for (int mt = 0; mt < 12; ++mt) {
                const int r = mt * 16 + l15;
                af[mt] = *(const f16x8*)&a[r * 32 + ((kb ^ ((r >> 1) & 3)) << 3)];
            }
            #pragma unroll
            for (int nt = 0; nt < 2; ++nt) {
                const int n = cb + nt * 16 + l15;
                bf[nt] = *(const f16x8*)&bw[n * 32 + ((kb ^ ((n >> 1) & 3)) << 3)];
            }
            #pragma unroll
            for (int mt = 0; mt < 12; ++mt)
                #pragma unroll
                for (int nt = 0; nt < 2; ++nt)
                    acc[mt * 2 + nt] = __builtin_amdgcn_mfma_f32_16x16x32_f16(af[mt], bf[nt], acc[mt * 2 + nt], 0, 0, 0);
        } else {
            f16x8 af[2], bf[12];
            #pragma unroll
            for (int mt = 0; mt < 2; ++mt) {
                const int n = cb + mt * 16 + l15;
                af[mt] = *(const f16x8*)&bw[n * 32 + ((kb ^ ((n >> 1) & 3)) << 3)];
            }
            #pragma unroll
            for (int nt = 0; nt < 12; ++nt) {
                const int r = nt * 16 + l15;
                bf[nt] = *(const f16x8*)&a[r * 32 + ((kb ^ ((r >> 1) & 3)) << 3)];
            }
            #pragma unroll
            for (int mt = 0; mt < 2; ++mt)
                #pragma unroll
                for (int nt = 0; nt < 12; ++nt)
                    acc[mt * 12 + nt] = __builtin_amdgcn_mfma_f32_16x16x32_f16(af[mt], bf[nt], acc[mt * 12 + nt], 0, 0, 0);
        }
    }

    if (w < 4) {
        ushort* dst = (w < 2) ? Qs : Ks;
        const int dbase = (w & 1) * 32;
        const int boff = (w < 2 ? 0 : 512) + h * 64;
        #pragma unroll
        for (int nt = 0; nt < 2; ++nt) {
            const int d = dbase + nt * 16 + l15;
            const float bv = bias[boff + d];
            #pragma unroll
            for (int mt = 0; mt < 12; ++mt)
                #pragma unroll
                for (int r = 0; r < 4; ++r) {
                    const int tok = mt * 16 + kb * 4 + r;
                    dst[tok * 64 + (((d >> 3) ^ (tok & 7)) << 3) + (d & 7)] =
                        f2h(acc[mt * 2 + nt][r] + bv);
                }
        }
    } else {
        const int dbase = (w - 4) * 32;
        #pragma unroll
        for (int mt = 0; mt < 2; ++mt)
            #pragma unroll
            for (int r = 0; r < 4; ++r) {
                const int d = dbase + mt * 16 + kb * 4 + r;
                const float bv = bias[1024 + h * 64 + d];
                const int sd = (d ^ (d >> 3)) & 7;
                #pragma unroll
                for (int nt = 0; nt < 12; ++nt) {
                    const int tok = nt * 16 + l15;
                    vt[d * 192 + (((tok >> 3) ^ sd) << 3) + (tok & 7)] =
                        f2h(acc[mt * 12 + nt][r] + bv);
                }
            }
    }
    __syncthreads();

    // -------- phase 2: attention, wave w handles q in [32w, 32w+32) --------
    {
        const int q0 = w * 32;
        const int q = q0 + l31;
        f16x8 qf[4];
        #pragma unroll
        for (int ds = 0; ds < 4; ++ds)
            qf[ds] = *(const f16x8*)&Qs[q * 64 + (((2 * ds + hi) ^ (q & 7)) << 3)];

        f32x16 S[6];
        #pragma unroll
        for (int kt = 0; kt < 6; ++kt)
            #pragma unroll
            for (int r = 0; r < 16; ++r) S[kt][r] = 0.f;
        __builtin_amdgcn_s_setprio(1);
        #pragma unroll
        for (int kt = 0; kt < 6; ++kt) {
            const int krow = kt * 32 + l31;
            #pragma unroll
            for (int ds = 0; ds < 4; ++ds) {
                f16x8 kf = *(const f16x8*)&Ks[krow * 64 + (((2 * ds + hi) ^ (krow & 7)) << 3)];
                S[kt] = __builtin_amdgcn_mfma_f32_32x32x16_f16(kf, qf[ds], S[kt], 0, 0, 0);
            }
        }
        __builtin_amdgcn_s_setprio(0);

        float mx = -1e30f;
        #pragma unroll
        for (int kt = 0; kt < 6; ++kt)
            #pragma unroll
            for (int r = 0; r < 16; ++r) {
                const int k = kt * 32 + (r & 3) + 8 * (r >> 2) + 4 * hi;
                float s = (k < NTOK) ? S[kt][r] * 0.125f + rs[k - q + 212] : -1e30f;
                S[kt][r] = s;
                mx = fmaxf(mx, s);
            }
        mx = fmaxf(mx, __shfl_xor(mx, 32));
        float sum = 0.f;
        #pragma unroll
        for (int kt = 0; kt < 6; ++kt)
            #pragma unroll
            for (int r = 0; r < 16; ++r) {
                float e = __expf(S[kt][r] - mx);
                S[kt][r] = e;
                sum += e;
            }
        sum += __shfl_xor(sum, 32);
        const float inv = 1.0f / sum;
        #pragma unroll
        for (int kt = 0; kt < 6; ++kt)
            #pragma unroll
            for (int r = 0; r < 16; ++r) S[kt][r] *= inv;

        f32x16 O[2];
        #pragma unroll
        for (int nt = 0; nt < 2; ++nt)
            #pragma unroll
            for (int r = 0; r < 16; ++r) O[nt][r] = 0.f;
        #pragma unroll
        for (int kt2 = 0; kt2 < 12; ++kt2) {
            const int kt = kt2 >> 1, half = kt2 & 1;
            uint p[4];
            #pragma unroll
            for (int m = 0; m < 4; ++m)
                p[m] = (uint)f2h(S[kt][8 * half + 2 * m]) |
                       ((uint)f2h(S[kt][8 * half + 2 * m + 1]) << 16);
            const uint s0l = (uint)__shfl_xor((int)p[0], 32);
            const uint s0h = (uint)__shfl_xor((int)p[1], 32);
            const uint s1l = (uint)__shfl_xor((int)p[2], 32);
            const uint s1h = (uint)__shfl_xor((int)p[3], 32);
            uint fa[4];
            if (hi == 0) { fa[0] = p[0]; fa[1] = p[1]; fa[2] = s0l; fa[3] = s0h; }
            else         { fa[0] = s1l; fa[1] = s1h; fa[2] = p[2]; fa[3] = p[3]; }
            const f16x8 pa = *(const f16x8*)fa;
            __builtin_amdgcn_s_setprio(1);
            #pragma unroll
            for (int nt = 0; nt < 2; ++nt) {
                const int d = nt * 32 + l31;
                f16x8 vf = *(const f16x8*)&vt[d * 192 + (((2 * kt2 + hi) ^ ((d ^ (d >> 3)) & 7)) << 3)];
                O[nt] = __builtin_amdgcn_mfma_f32_32x32x16_f16(pa, vf, O[nt], 0, 0, 0);
            }
            __builtin_amdgcn_s_setprio(0);
        }

        #pragma unroll
        for (int nt = 0; nt < 2; ++nt)
            #pragma unroll
            for (int r = 0; r < 16; ++r) {
                const int qr = q0 + (r & 3) + 8 * (r >> 2) + 4 * hi;
                if (qr < NTOK)
                    outb[(size_t)(b * NTOK + qr) * 512 + h * 64 + nt * 32 + l31] = f2h(O[nt][r]);
            }
    }
}

// ------- xb = f16( LN(xb + y0 + y1) * g + b ) ; f16 residual stream -----------
template<int NY>
__global__ __launch_bounds__(256) void lnres_kernel(ushort* __restrict__ xb,
                                                    const ushort* __restrict__ y,
                                                    const ushort* __restrict__ y1,
                                                    const float* __restrict__ g, const float* __restrict__ bb) {
    const int row = blockIdx.x * 4 + (threadIdx.x >> 6);
    const int l = threadIdx.x & 63;
    ushort* xbr = xb + (size_t)row * 512;
    const ushort* yr = y + (size_t)row * 512;
    const ushort4 a0 = *(const ushort4*)(xbr + (l << 2));
    const ushort4 a1 = *(const ushort4*)(xbr + 256 + (l << 2));
    const ushort4 u0 = *(const ushort4*)(yr + (l << 2));
    const ushort4 u1 = *(const ushort4*)(yr + 256 + (l << 2));
    float4 v0 = make_float4(h2f(a0.x) + h2f(u0.x), h2f(a0.y) + h2f(u0.y),
                            h2f(a0.z) + h2f(u0.z), h2f(a0.w) + h2f(u0.w));
    float4 v1 = make_float4(h2f(a1.x) + h2f(u1.x), h2f(a1.y) + h2f(u1.y),
                            h2f(a1.z) + h2f(u1.z), h2f(a1.w) + h2f(u1.w));
    if (NY == 2) {
        const ushort* y1r = y1 + (size_t)row * 512;
        const ushort4 w0 = *(const ushort4*)(y1r + (l << 2));
        const ushort4 w1 = *(const ushort4*)(y1r + 256 + (l << 2));
        v0.x += h2f(w0.x); v0.y += h2f(w0.y); v0.z += h2f(w0.z); v0.w += h2f(w0.w);
        v1.x += h2f(w1.x); v1.y += h2f(w1.y); v1.z += h2f(w1.z); v1.w += h2f(w1.w);
    }
    float s = v0.x + v0.y + v0.z + v0.w + v1.x + v1.y + v1.z + v1.w;
    #pragma unroll
    for (int off = 32; off; off >>= 1) s += __shfl_xor(s, off);
    const float m = s * (1.0f / 512.0f);
    float d0 = v0.x - m, d1 = v0.y - m, d2 = v0.z - m, d3 = v0.w - m;
    float d4 = v1.x - m, d5 = v1.y - m, d6 = v1.z - m, d7 = v1.w - m;
    float q = d0*d0 + d1*d1 + d2*d2 + d3*d3 + d4*d4 + d5*d5 + d6*d6 + d7*d7;
    #pragma unroll
    for (int off = 32; off; off >>= 1) q += __shfl_xor(q, off);
    const float r = rsqrtf(q * (1.0f / 512.0f) + 1e-5f);
    const float4 g0 = *(const float4*)(g + (l << 2));
    const float4 g1 = *(const float4*)(g + 256 + (l << 2));
    const float4 b0 = *(const float4*)(bb + (l << 2));
    const float4 b1 = *(const float4*)(bb + 256 + (l << 2));
    float4 o0, o1;
    o0.x = d0 * r * g0.x + b0.x; o0.y = d1 * r * g0.y + b0.y;
    o0.z = d2 * r * g0.z + b0.z; o0.w = d3 * r * g0.w + b0.w;
    o1.x = d4 * r * g1.x + b1.x; o1.y = d5 * r * g1.y + b1.y;
    o1.z = d6 * r * g1.z + b1.z; o1.w = d7 * r * g1.w + b1.w;
    *(ushort4*)(xbr + (l << 2)) = make_ushort4(f2h(o0.x), f2h(o0.y), f2h(o0.z), f2h(o0.w));
    *(ushort4*)(xbr + 256 + (l << 2)) = make_ushort4(f2h(o1.x), f2h(o1.y), f2h(o1.z), f2h(o1.w));
}

// ---------------- bilinear warp ----------------------------------------------
__global__ void warp_kernel(const float* __restrict__ x0, const float* __restrict__ shift,
                            const int* __restrict__ pms, float* __restrict__ warped) {
    int idx = blockIdx.x * 256 + threadIdx.x;
    if (idx >= M_ROWS * 512) return;
    int c = idx & 511;
    int m = idx >> 9;
    int t = m % NTOK;
    int b = m / NTOK;
    float max_shift = (float)pms[0];
    float sh = shift[m];
    float flow = sh * max_shift / 256.0f;
    float gx = 2.0f * ((float)c / 511.0f - 0.5f) + flow;
    float ix = ((gx + 1.0f) * 512.0f - 1.0f) * 0.5f;
    ix = fminf(fmaxf(ix, 0.0f), 511.0f);
    float gy = 2.0f * ((float)t / 180.0f - 0.5f);
    float iy = ((gy + 1.0f) * 181.0f - 1.0f) * 0.5f;
    iy = fminf(fmaxf(iy, 0.0f), 180.0f);
    float ix0f = floorf(ix), iy0f = floorf(iy);
    float wx = ix - ix0f, wy = iy - iy0f;
    int ix0 = min(max((int)ix0f, 0), 511);
    int ix1 = min(ix0 + 1, 511);
    int iy0 = min(max((int)iy0f, 0), 180);
    int iy1 = min(iy0 + 1, 180);
    const float* xb = x0 + (size_t)b * NTOK * 512;
    float v00 = xb[iy0 * 512 + ix0], v01 = xb[iy0 * 512 + ix1];
    float v10 = xb[iy1 * 512 + ix0], v11 = xb[iy1 * 512 + ix1];
    warped[idx] = (1.f - wy) * ((1.f - wx) * v00 + wx * v01) + wy * ((1.f - wx) * v10 + wx * v11);
}

extern "C" void kernel_launch(void* const* d_in, const int* in_sizes, int n_in,
                              void* d_out, int out_size, void* d_ws, size_t ws_size,
                              hipStream_t stream) {
    const float* x0   = (const float*)d_in[0];
    const int*   pms  = (const int*)d_in[1];
    const float* pos  = (const float*)d_in[2];
    const float* qkvw = (const float*)d_in[3];
    const float* qkvb = (const float*)d_in[4];
    const float* outw = (const float*)d_in[5];
    const float* outbp= (const float*)d_in[6];
    const float* relp = (const float*)d_in[7];
    const float* rpew = (const float*)d_in[8];
    const float* ln1g = (const float*)d_in[9];
    const float* ln1b = (const float*)d_in[10];
    const float* fw1  = (const float*)d_in[11];
    const float* fb1  = (const float*)d_in[12];
    const float* fw2  = (const float*)d_in[13];
    const float* fb2  = (const float*)d_in[14];
    const float* ln2g = (const float*)d_in[15];
    const float* ln2b = (const float*)d_in[16];
    const float* mw1  = (const float*)d_in[17];
    const float* mb1  = (const float*)d_in[18];
    const float* mw2  = (const float*)d_in[19];
    const float* mb2  = (const float*)d_in[20];

    float* out = (float*)d_out;

    char* ws = (char*)d_ws;
    ushort* xb    = (ushort*)(ws + 11862016);                 //  5,931,008 B (f16 residual)
    char*   qr    = ws + 11862016 + 5931008;
    ushort* ybuf  = (ushort*)qr;                              // f16 partial 0 (5.9MB)
    ushort* ybuf2 = (ushort*)(qr + 5931008);                  // f16 partial 1 (5.9MB)
    ushort* hbuf  = (ushort*)(qr + 11862016);                 // 23.7MB (ffn hidden)
    ushort* attnb = (ushort*)(qr + 35586048);                 //  5,931,008 B
    float*  rbias = (float*)(qr + 35586048 + 5931008);        //  6*512*4 B
    ushort* wts   = (ushort*)(qr + 35586048 + 5931008 + 12288);
    ushort* qkv_wt = wts;                                     // 6*1536*512
    ushort* out_wt = qkv_wt + 6 * 1536 * 512;                 // 6*512*512
    ushort* f1_wt  = out_wt + 6 * 512 * 512;                  // 6*2048*512
    ushort* f2_wt  = f1_wt  + 6 * 512 * 2048;                 // 6*512*2048
    ushort* w1t    = f2_wt  + 6 * 2048 * 512;                 // 64*512

    hipFuncSetAttribute((const void*)attn_fused,
                        hipFuncAttributeMaxDynamicSharedMemorySize, 124544);

    // single-dispatch prologue (5 transposes + rbias + add_pos)
    wt_all<<<7524, 256, 0, stream>>>(qkvw, outw, fw1, fw2, mw1, relp, rpew, x0, pos,
                                     qkv_wt, out_wt, f1_wt, f2_wt, w1t, rbias, xb);

    const int g_ffn1 = 96 * 16;        // BM=64, N=2048
    const int g_np4  = 96 * 4;         // BM=64, N=512
    for (int i = 0; i < NLAYER; ++i) {
        attn_fused<<<256, 384, 124544, stream>>>(xb, qkv_wt + (size_t)i * 1536 * 512,
                                                 qkvb + i * 1536, rbias + i * 512, attnb);
        mfma_gemm<64, 2, 2><<<g_np4 * 2, 256, 0, stream>>>(attnb, out_wt + (size_t)i * 512 * 512,
                                                           outbp + i * 512, ybuf, M_ROWS, 512, 512);
        lnres_kernel<2><<<1448, 256, 0, stream>>>(xb, ybuf, ybuf2, ln1g + i * 512, ln1b + i * 512);
        mfma_gemm<64, 1, 1><<<g_ffn1, 256, 0, stream>>>(xb, f1_wt + (size_t)i * 2048 * 512,
                                                        fb1 + i * 2048, hbuf, M_ROWS, 512, 2048);
        mfma_gemm<64, 2, 2><<<g_np4 * 2, 256, 0, stream>>>(hbuf, f2_wt + (size_t)i * 512 * 2048,
                                                           fb2 + i * 512, ybuf, M_ROWS, 2048, 512);
        lnres_kernel<2><<<1448, 256, 0, stream>>>(xb, ybuf, ybuf2, ln2g + i * 512, ln2b + i * 512);
    }

    head_mfma<<<46, 256, 0, stream>>>(xb, w1t, mb1, mw2, mb2, out);
    warp_kernel<<<(M_ROWS * 512 + 255) / 256, 256, 0, stream>>>(x0, out, pms, out + M_ROWS);
}

// Round 17
// 633.422 us; speedup vs baseline: 1.5280x; 1.0263x over previous
//
#include <hip/hip_runtime.h>
#include <hip/hip_bf16.h>
#include <math.h>

#define M_ROWS 5792   // B*N
#define NTOK 181
#define NLAYER 6

typedef __attribute__((ext_vector_type(8))) _Float16 f16x8;
typedef __attribute__((ext_vector_type(4))) float f32x4;
typedef __attribute__((ext_vector_type(16))) float f32x16;

__device__ __forceinline__ ushort f2h(float f) {
    union { _Float16 h; ushort u; } v;
    v.h = (_Float16)f;
    return v.u;
}
__device__ __forceinline__ float h2f(ushort u) {
    union { ushort u; _Float16 h; } v; v.u = u;
    return (float)v.h;
}
__device__ __forceinline__ float gelu_f(float v) {
    return 0.5f * v * (1.0f + erff(v * 0.70710678118654752f));
}
__device__ __forceinline__ void async16(const void* g, void* l) {
    __builtin_amdgcn_global_load_lds((const __attribute__((address_space(1))) void*)g,
                                     (__attribute__((address_space(3))) void*)l, 16, 0, 0);
}

// ---- combined prologue: 5 weight transposes + rbias + add_pos ----------------
__global__ __launch_bounds__(256) void wt_all(const float* __restrict__ qkvw,
                                              const float* __restrict__ outw,
                                              const float* __restrict__ fw1,
                                              const float* __restrict__ fw2,
                                              const float* __restrict__ mw1,
                                              const float* __restrict__ relp,
                                              const float* __restrict__ rpew,
                                              const float* __restrict__ x0,
                                              const float* __restrict__ pos,
                                              ushort* __restrict__ qkv_wt, ushort* __restrict__ out_wt,
                                              ushort* __restrict__ f1_wt, ushort* __restrict__ f2_wt,
                                              ushort* __restrict__ w1t, float* __restrict__ rbias,
                                              ushort* __restrict__ xb) {
    int id = blockIdx.x;
    if (id >= 4628) {                      // add_pos
        const int idx = (id - 4628) * 256 + threadIdx.x;   // float4 index
        if (idx >= M_ROWS * 128) return;
        const int col = idx & 127;
        const int m   = idx >> 7;
        const int t   = m % NTOK;
        float4 a = ((const float4*)x0)[idx];
        float4 p = ((const float4*)pos)[t * 128 + col];
        a.x += p.x; a.y += p.y; a.z += p.z; a.w += p.w;
        ((ushort4*)xb)[idx] = make_ushort4(f2h(a.x), f2h(a.y), f2h(a.z), f2h(a.w));
        return;
    }
    if (id >= 4616) {                      // rbias
        id -= 4616;
        const int l = id >> 1;
        const int j = (id & 1) * 256 + threadIdx.x;
        if (j >= 2 * NTOK - 1) return;
        const float* rp = relp + ((size_t)l * (2 * NTOK - 1) + j) * 64;
        const float* wv = rpew + l * 64;
        float s = 0.f;
        #pragma unroll
        for (int d = 0; d < 64; d += 4) {
            float4 a = *(const float4*)(rp + d);
            float4 b = *(const float4*)(wv + d);
            s += a.x*b.x + a.y*b.y + a.z*b.z + a.w*b.w;
        }
        rbias[l * 512 + j] = s;
        return;
    }
    const float* W; ushort* Wt; int K, N;
    if (id < 1152)      { W = qkvw; Wt = qkv_wt; K = 512;  N = 1536; }
    else if (id < 1536) { W = outw; Wt = out_wt; K = 512;  N = 512;  id -= 1152; }
    else if (id < 3072) { W = fw1;  Wt = f1_wt;  K = 512;  N = 2048; id -= 1536; }
    else if (id < 4608) { W = fw2;  Wt = f2_wt;  K = 2048; N = 512;  id -= 3072; }
    else                { W = mw1;  Wt = w1t;    K = 512;  N = 64;   id -= 4608; }
    const int nk = K >> 6, nn = N >> 6;
    const int per = nk * nn;
    const int z = id / per; id -= z * per;
    const int k0 = (id % nk) * 64, n0 = (id / nk) * 64;

    __shared__ float t[64][65];
    const size_t ls = (size_t)z * K * N;
    const float* Wl = W + ls;
    ushort* Wtl = Wt + ls;
    const int tr = threadIdx.x >> 6, tc = threadIdx.x & 63;
    #pragma unroll
    for (int i = 0; i < 16; ++i) {
        const int r = i * 4 + tr;
        t[r][tc] = Wl[(size_t)(k0 + r) * N + n0 + tc];
    }
    __syncthreads();
    #pragma unroll
    for (int i = 0; i < 16; ++i) {
        const int r = i * 4 + tr;
        Wtl[(size_t)(n0 + r) * K + k0 + tc] = f2h(t[tc][r]);
    }
}

// ---------------- f16 MFMA GEMM: XCD swizzle, optional split-K ----------------
template<int BM, int EPI, int SK>
__global__ __launch_bounds__(256) void mfma_gemm(const ushort* __restrict__ A,
                                                 const ushort* __restrict__ Bt,
                                                 const float* __restrict__ bias,
                                                 void* __restrict__ Cv,
                                                 int M, int K, int N) {
    constexpr int MREP = BM / 32;
    __shared__ __align__(16) ushort sA[2][BM * 32];
    __shared__ __align__(16) ushort sB[2][128 * 32];

    const int NC  = N >> 7;
    const int NR  = (M + BM - 1) / BM;
    const int NRP = (NR + 7) & ~7;
    const int PSB = NRP * NC;
    const int gid = blockIdx.x;
    const int sk  = (SK > 1) ? gid / PSB : 0;
    const int j   = (SK > 1) ? gid % PSB : gid;
    const int r   = (j / (8 * NC)) * 8 + (j & 7);
    const int c   = (j % (8 * NC)) >> 3;
    if (r >= NR) return;

    const int tid = threadIdx.x;
    const int lane = tid & 63;
    const int w = tid >> 6;
    const int wr = w >> 1, wc = w & 1;
    const int row0 = r * BM, col0 = c * 128;
    const int wbase = tid & ~63;

    f32x4 acc[MREP][4];
    const f32x4 zero = {0.f, 0.f, 0.f, 0.f};
    #pragma unroll
    for (int m = 0; m < MREP; ++m)
        #pragma unroll
        for (int n = 0; n < 4; ++n) acc[m][n] = zero;

    auto stage = [&](int buf, int kt) {
        const int k0 = kt << 5;
        #pragma unroll
        for (int i = 0; i < BM / 64; ++i) {
            const int s = i * 256 + tid;
            const int row = s >> 2;
            const int kbl = (s & 3) ^ ((row >> 1) & 3);
            int gr = row0 + row; if (gr > M - 1) gr = M - 1;
            async16(A + (size_t)gr * K + k0 + (kbl << 3),
                    &sA[buf][(i * 256 + wbase) * 8]);
        }
        #pragma unroll
        for (int i = 0; i < 2; ++i) {
            const int s = i * 256 + tid;
            const int nr = s >> 2;
            const int kbl = (s & 3) ^ ((nr >> 1) & 3);
            async16(Bt + (size_t)(col0 + nr) * K + k0 + (kbl << 3),
                    &sB[buf][(i * 256 + wbase) * 8]);
        }
    };

    const int NIT = (K / SK) >> 5;
    const int kt0 = sk * NIT;
    stage(0, kt0);
    const int l15 = lane & 15, kb = lane >> 4;
    for (int it = 0; it < NIT; ++it) {
        __syncthreads();
        if (it + 1 < NIT) stage((it + 1) & 1, kt0 + it + 1);
        const int buf = it & 1;
        f16x8 af[MREP], bfr[4];
        #pragma unroll
        for (int m = 0; m < MREP; ++m) {
            const int rr = wr * (BM / 2) + m * 16 + l15;
            af[m] = *(const f16x8*)&sA[buf][rr * 32 + ((kb ^ ((rr >> 1) & 3)) << 3)];
        }
        #pragma unroll
        for (int n = 0; n < 4; ++n) {
            const int rr = wc * 64 + n * 16 + l15;
            bfr[n] = *(const f16x8*)&sB[buf][rr * 32 + ((kb ^ ((rr >> 1) & 3)) << 3)];
        }
        #pragma unroll
        for (int m = 0; m < MREP; ++m)
            #pragma unroll
            for (int n = 0; n < 4; ++n)
                acc[m][n] = __builtin_amdgcn_mfma_f32_16x16x32_f16(af[m], bfr[n], acc[m][n], 0, 0, 0);
    }

    const int crow = row0 + wr * (BM / 2) + (lane >> 4) * 4;
    const int ccol = col0 + wc * 64 + l15;
    ushort* outh = (ushort*)Cv + (size_t)sk * M * N;
    #pragma unroll
    for (int m = 0; m < MREP; ++m)
        #pragma unroll
        for (int n = 0; n < 4; ++n) {
            const int gc = ccol + n * 16;
            const float bv = (SK == 1 || sk == 0) ? bias[gc] : 0.f;
            #pragma unroll
            for (int rr = 0; rr < 4; ++rr) {
                const int gr = crow + m * 16 + rr;
                if (gr < M) {
                    float v = acc[m][n][rr] + bv;
                    if (EPI == 1)      outh[(size_t)gr * N + gc] = f2h(gelu_f(v));
                    else if (EPI == 2) outh[(size_t)gr * N + gc] = f2h(v);
                    else               ((float*)Cv)[(size_t)gr * N + gc] = v;
                }
            }
        }
}

// ---------------- head MLP via MFMA ------------------------------------------
__global__ __launch_bounds__(256) void head_mfma(const ushort* __restrict__ A,
                                                 const ushort* __restrict__ Bt,
                                                 const float* __restrict__ b1,
                                                 const float* __restrict__ w2,
                                                 const float* __restrict__ b2,
                                                 float* __restrict__ shift) {
    const int M = M_ROWS, K = 512;
    __shared__ __align__(16) ushort sA[2][128 * 32];
    __shared__ __align__(16) ushort sB[2][64 * 32];
    const int tid = threadIdx.x;
    const int lane = tid & 63;
    const int w = tid >> 6;
    const int row0 = blockIdx.x * 128;
    const int wbase = tid & ~63;

    f32x4 acc[2][4];
    const f32x4 zero = {0.f, 0.f, 0.f, 0.f};
    #pragma unroll
    for (int m = 0; m < 2; ++m)
        #pragma unroll
        for (int n = 0; n < 4; ++n) acc[m][n] = zero;

    auto stage = [&](int buf, int kt) {
        const int k0 = kt << 5;
        #pragma unroll
        for (int i = 0; i < 2; ++i) {
            const int s = i * 256 + tid;
            const int row = s >> 2;
            const int kbl = (s & 3) ^ ((row >> 1) & 3);
            int gr = row0 + row; if (gr > M - 1) gr = M - 1;
            async16(A + (size_t)gr * K + k0 + (kbl << 3),
                    &sA[buf][(i * 256 + wbase) * 8]);
        }
        {
            const int s = tid;
            const int nr = s >> 2;
            const int kbl = (s & 3) ^ ((nr >> 1) & 3);
            async16(Bt + (size_t)nr * K + k0 + (kbl << 3),
                    &sB[buf][wbase * 8]);
        }
    };

    stage(0, 0);
    const int l15 = lane & 15, kb = lane >> 4;
    for (int it = 0; it < 16; ++it) {
        __syncthreads();
        if (it + 1 < 16) stage((it + 1) & 1, it + 1);
        const int buf = it & 1;
        f16x8 af[2], bfr[4];
        #pragma unroll
        for (int m = 0; m < 2; ++m) {
            const int r = w * 32 + m * 16 + l15;
            af[m] = *(const f16x8*)&sA[buf][r * 32 + ((kb ^ ((r >> 1) & 3)) << 3)];
        }
        #pragma unroll
        for (int n = 0; n < 4; ++n) {
            const int r = n * 16 + l15;
            bfr[n] = *(const f16x8*)&sB[buf][r * 32 + ((kb ^ ((r >> 1) & 3)) << 3)];
        }
        #pragma unroll
        for (int m = 0; m < 2; ++m)
            #pragma unroll
            for (int n = 0; n < 4; ++n)
                acc[m][n] = __builtin_amdgcn_mfma_f32_16x16x32_f16(af[m], bfr[n], acc[m][n], 0, 0, 0);
    }

    const float b2v = b2[0];
    float b1v[4], w2v[4];
    #pragma unroll
    for (int n = 0; n < 4; ++n) {
        const int c = n * 16 + l15;
        b1v[n] = b1[c];
        w2v[n] = w2[c];
    }
    #pragma unroll
    for (int m = 0; m < 2; ++m) {
        #pragma unroll
        for (int r = 0; r < 4; ++r) {
            float p = 0.f;
            #pragma unroll
            for (int n = 0; n < 4; ++n)
                p += fmaxf(acc[m][n][r] + b1v[n], 0.f) * w2v[n];
            #pragma unroll
            for (int off = 1; off < 16; off <<= 1) p += __shfl_xor(p, off);
            const int gr = row0 + w * 32 + m * 16 + kb * 4 + r;
            if (l15 == 0 && gr < M) shift[gr] = p + b2v;
        }
    }
}

// ============== FUSED qkv-GEMM + attention: one block per (b,h), 6 waves ======
// b-grouped decode: all 8 head-blocks of batch b share id%8 -> same XCD, so the
// shared A-panel (xb rows of b) is fetched into that XCD's L2 once.
__global__ __launch_bounds__(384, 1) void attn_fused(const ushort* __restrict__ xb,
                                                     const ushort* __restrict__ Wt,
                                                     const float* __restrict__ bias,
                                                     const float* __restrict__ rb,
                                                     ushort* __restrict__ outb) {
    extern __shared__ __align__(16) char smem[];
    ushort* Ks = (ushort*)smem;             // [192][64]
    ushort* Qs = Ks + 12288;                // [192][64]
    ushort* vt = Qs + 12288;                // [64][192]
    ushort* sA = vt + 12288;                // 2 x 192x32
    ushort* sB = sA + 12288;                // 2 x 192x32
    float*  rs = (float*)(smem + 122880);   // 416 floats

    const int b = blockIdx.x & 31;
    const int h = blockIdx.x >> 5;
    const int tid = threadIdx.x, lane = tid & 63, w = tid >> 6;   // w in 0..5
    const int l31 = lane & 31, hi = lane >> 5;
    const int l15 = lane & 15, kb = lane >> 4;
    const int wbase = tid & ~63;

    for (int i = tid; i < 416; i += 384) {
        int j = i - 32;
        rs[i] = (j >= 0 && j < 2 * NTOK - 1) ? rb[j] : 0.f;
    }

    const ushort* Arow = xb + (size_t)(b * NTOK) * 512;

    auto stage = [&](int buf, int it) {
        const int k0 = it << 5;
        #pragma unroll
        for (int i = 0; i < 2; ++i) {
            const int s = i * 384 + tid;
            const int row = s >> 2;
            const int kbl = (s & 3) ^ ((row >> 1) & 3);
            const int gr = row < NTOK ? row : NTOK - 1;
            async16(Arow + (size_t)gr * 512 + k0 + (kbl << 3),
                    &sA[buf * 6144 + (i * 384 + wbase) * 8]);
        }
        #pragma unroll
        for (int i = 0; i < 2; ++i) {
            const int s = i * 384 + tid;
            const int n = s >> 2;
            const int kbl = (s & 3) ^ ((n >> 1) & 3);
            const int wrow = (n >> 6) * 512 + h * 64 + (n & 63);
            async16(Wt + (size_t)wrow * 512 + k0 + (kbl << 3),
                    &sB[buf * 6144 + (i * 384 + wbase) * 8]);
        }
    };

    // -------- phase 1: GEMM, 24 acc tiles per wave --------
    f32x4 acc[24];
    const f32x4 zero = {0.f, 0.f, 0.f, 0.f};
    #pragma unroll
    for (int t = 0; t < 24; ++t) acc[t] = zero;

    const int cb = (w < 4) ? ((w >> 1) * 64 + (w & 1) * 32)
                           : (128 + (w - 4) * 32);

    stage(0, 0);
    for (int it = 0; it < 16; ++it) {
        __syncthreads();
        if (it + 1 < 16) stage((it + 1) & 1, it + 1);
        const ushort* a  = &sA[(it & 1) * 6144];
        const ushort* bw = &sB[(it & 1) * 6144];
        if (w < 4) {
            f16x8 af[12], bf[2];
            #pragma unroll
            for (int mt = 0; mt < 12; ++mt) {
                const int r = mt * 16 + l15;
                af[mt] = *(const f16x8*)&a[r * 32 + ((kb ^ ((r >> 1) & 3)) << 3)];
            }
            #pragma unroll
            for (int nt = 0; nt < 2; ++nt) {
                const int n = cb + nt * 16 + l15;
                bf[nt] = *(const f16x8*)&bw[n * 32 + ((kb ^ ((n >> 1) & 3)) << 3)];
            }
            #pragma unroll
            for (int mt = 0; mt < 12; ++mt)
                #pragma unroll
                for (int nt = 0; nt < 2; ++nt)
                    acc[mt * 2 + nt] = __builtin_amdgcn_mfma_f32_16x16x32_f16(af[mt], bf[nt], acc[mt * 2 + nt], 0, 0, 0);
        } else {
            f16x8 af[2], bf[12];
            #pragma unroll
            for (int mt = 0; mt < 2; ++mt) {
                const int n = cb + mt * 16 + l15;
                af[mt] = *(const f16x8*)&bw[n * 32 + ((kb ^ ((n >> 1) & 3)) << 3)];
            }
            #pragma unroll
            for (int nt = 0; nt < 12; ++nt) {
                const int r = nt * 16 + l15;
                bf[nt] = *(const f16x8*)&a[r * 32 + ((kb ^ ((r >> 1) & 3)) << 3)];
            }
            #pragma unroll
            for (int mt = 0; mt < 2; ++mt)
                #pragma unroll
                for (int nt = 0; nt < 12; ++nt)
                    acc[mt * 12 + nt] = __builtin_amdgcn_mfma_f32_16x16x32_f16(af[mt], bf[nt], acc[mt * 12 + nt], 0, 0, 0);
        }
    }

    if (w < 4) {
        ushort* dst = (w < 2) ? Qs : Ks;
        const int dbase = (w & 1) * 32;
        const int boff = (w < 2 ? 0 : 512) + h * 64;
        #pragma unroll
        for (int nt = 0; nt < 2; ++nt) {
            const int d = dbase + nt * 16 + l15;
            const float bv = bias[boff + d];
            #pragma unroll
            for (int mt = 0; mt < 12; ++mt)
                #pragma unroll
                for (int r = 0; r < 4; ++r) {
                    const int tok = mt * 16 + kb * 4 + r;
                    dst[tok * 64 + (((d >> 3) ^ (tok & 7)) << 3) + (d & 7)] =
                        f2h(acc[mt * 2 + nt][r] + bv);
                }
        }
    } else {
        const int dbase = (w - 4) * 32;
        #pragma unroll
        for (int mt = 0; mt < 2; ++mt)
            #pragma unroll
            for (int r = 0; r < 4; ++r) {
                const int d = dbase + mt * 16 + kb * 4 + r;
                const float bv = bias[1024 + h * 64 + d];
                const int sd = (d ^ (d >> 3)) & 7;
                #pragma unroll
                for (int nt = 0; nt < 12; ++nt) {
                    const int tok = nt * 16 + l15;
                    vt[d * 192 + (((tok >> 3) ^ sd) << 3) + (tok & 7)] =
                        f2h(acc[mt * 12 + nt][r] + bv);
                }
            }
    }
    __syncthreads();

    // -------- phase 2: attention, wave w handles q in [32w, 32w+32) --------
    {
        const int q0 = w * 32;
        const int q = q0 + l31;
        f16x8 qf[4];
        #pragma unroll
        for (int ds = 0; ds < 4; ++ds)
            qf[ds] = *(const f16x8*)&Qs[q * 64 + (((2 * ds + hi) ^ (q & 7)) << 3)];

        f32x16 S[6];
        #pragma unroll
        for (int kt = 0; kt < 6; ++kt)
            #pragma unroll
            for (int r = 0; r < 16; ++r) S[kt][r] = 0.f;
        __builtin_amdgcn_s_setprio(1);
        #pragma unroll
        for (int kt = 0; kt < 6; ++kt) {
            const int krow = kt * 32 + l31;
            #pragma unroll
            for (int ds = 0; ds < 4; ++ds) {
                f16x8 kf = *(const f16x8*)&Ks[krow * 64 + (((2 * ds + hi) ^ (krow & 7)) << 3)];
                S[kt] = __builtin_amdgcn_mfma_f32_32x32x16_f16(kf, qf[ds], S[kt], 0, 0, 0);
            }
        }
        __builtin_amdgcn_s_setprio(0);

        float mx = -1e30f;
        #pragma unroll
        for (int kt = 0; kt < 6; ++kt)
            #pragma unroll
            for (int r = 0; r < 16; ++r) {
                const int k = kt * 32 + (r & 3) + 8 * (r >> 2) + 4 * hi;
                float s = (k < NTOK) ? S[kt][r] * 0.125f + rs[k - q + 212] : -1e30f;
                S[kt][r] = s;
                mx = fmaxf(mx, s);
            }
        mx = fmaxf(mx, __shfl_xor(mx, 32));
        float sum = 0.f;
        #pragma unroll
        for (int kt = 0; kt < 6; ++kt)
            #pragma unroll
            for (int r = 0; r < 16; ++r) {
                float e = __expf(S[kt][r] - mx);
                S[kt][r] = e;
                sum += e;
            }
        sum += __shfl_xor(sum, 32);
        const float inv = 1.0f / sum;
        #pragma unroll
        for (int kt = 0; kt < 6; ++kt)
            #pragma unroll
            for (int r = 0; r < 16; ++r) S[kt][r] *= inv;

        f32x16 O[2];
        #pragma unroll
        for (int nt = 0; nt < 2; ++nt)
            #pragma unroll
            for (int r = 0; r < 16; ++r) O[nt][r] = 0.f;
        #pragma unroll
        for (int kt2 = 0; kt2 < 12; ++kt2) {
            const int kt = kt2 >> 1, half = kt2 & 1;
            uint p[4];
            #pragma unroll
            for (int m = 0; m < 4; ++m)
                p[m] = (uint)f2h(S[kt][8 * half + 2 * m]) |
                       ((uint)f2h(S[kt][8 * half + 2 * m + 1]) << 16);
            const uint s0l = (uint)__shfl_xor((int)p[0], 32);
            const uint s0h = (uint)__shfl_xor((int)p[1], 32);
            const uint s1l = (uint)__shfl_xor((int)p[2], 32);
            const uint s1h = (uint)__shfl_xor((int)p[3], 32);
            uint fa[4];
            if (hi == 0) { fa[0] = p[0]; fa[1] = p[1]; fa[2] = s0l; fa[3] = s0h; }
            else         { fa[0] = s1l; fa[1] = s1h; fa[2] = p[2]; fa[3] = p[3]; }
            const f16x8 pa = *(const f16x8*)fa;
            __builtin_amdgcn_s_setprio(1);
            #pragma unroll
            for (int nt = 0; nt < 2; ++nt) {
                const int d = nt * 32 + l31;
                f16x8 vf = *(const f16x8*)&vt[d * 192 + (((2 * kt2 + hi) ^ ((d ^ (d >> 3)) & 7)) << 3)];
                O[nt] = __builtin_amdgcn_mfma_f32_32x32x16_f16(pa, vf, O[nt], 0, 0, 0);
            }
            __builtin_amdgcn_s_setprio(0);
        }

        #pragma unroll
        for (int nt = 0; nt < 2; ++nt)
            #pragma unroll
            for (int r = 0; r < 16; ++r) {
                const int qr = q0 + (r & 3) + 8 * (r >> 2) + 4 * hi;
                if (qr < NTOK)
                    outb[(size_t)(b * NTOK + qr) * 512 + h * 64 + nt * 32 + l31] = f2h(O[nt][r]);
            }
    }
}

// ------- xb = f16( LN(xb + y0 + y1) * g + b ) ; f16 residual stream -----------
template<int NY>
__global__ __launch_bounds__(256) void lnres_kernel(ushort* __restrict__ xb,
                                                    const ushort* __restrict__ y,
                                                    const ushort* __restrict__ y1,
                                                    const float* __restrict__ g, const float* __restrict__ bb) {
    const int row = blockIdx.x * 4 + (threadIdx.x >> 6);
    const int l = threadIdx.x & 63;
    ushort* xbr = xb + (size_t)row * 512;
    const ushort* yr = y + (size_t)row * 512;
    const ushort4 a0 = *(const ushort4*)(xbr + (l << 2));
    const ushort4 a1 = *(const ushort4*)(xbr + 256 + (l << 2));
    const ushort4 u0 = *(const ushort4*)(yr + (l << 2));
    const ushort4 u1 = *(const ushort4*)(yr + 256 + (l << 2));
    float4 v0 = make_float4(h2f(a0.x) + h2f(u0.x), h2f(a0.y) + h2f(u0.y),
                            h2f(a0.z) + h2f(u0.z), h2f(a0.w) + h2f(u0.w));
    float4 v1 = make_float4(h2f(a1.x) + h2f(u1.x), h2f(a1.y) + h2f(u1.y),
                            h2f(a1.z) + h2f(u1.z), h2f(a1.w) + h2f(u1.w));
    if (NY == 2) {
        const ushort* y1r = y1 + (size_t)row * 512;
        const ushort4 w0 = *(const ushort4*)(y1r + (l << 2));
        const ushort4 w1 = *(const ushort4*)(y1r + 256 + (l << 2));
        v0.x += h2f(w0.x); v0.y += h2f(w0.y); v0.z += h2f(w0.z); v0.w += h2f(w0.w);
        v1.x += h2f(w1.x); v1.y += h2f(w1.y); v1.z += h2f(w1.z); v1.w += h2f(w1.w);
    }
    float s = v0.x + v0.y + v0.z + v0.w + v1.x + v1.y + v1.z + v1.w;
    #pragma unroll
    for (int off = 32; off; off >>= 1) s += __shfl_xor(s, off);
    const float m = s * (1.0f / 512.0f);
    float d0 = v0.x - m, d1 = v0.y - m, d2 = v0.z - m, d3 = v0.w - m;
    float d4 = v1.x - m, d5 = v1.y - m, d6 = v1.z - m, d7 = v1.w - m;
    float q = d0*d0 + d1*d1 + d2*d2 + d3*d3 + d4*d4 + d5*d5 + d6*d6 + d7*d7;
    #pragma unroll
    for (int off = 32; off; off >>= 1) q += __shfl_xor(q, off);
    const float r = rsqrtf(q * (1.0f / 512.0f) + 1e-5f);
    const float4 g0 = *(const float4*)(g + (l << 2));
    const float4 g1 = *(const float4*)(g + 256 + (l << 2));
    const float4 b0 = *(const float4*)(bb + (l << 2));
    const float4 b1 = *(const float4*)(bb + 256 + (l << 2));
    float4 o0, o1;
    o0.x = d0 * r * g0.x + b0.x; o0.y = d1 * r * g0.y + b0.y;
    o0.z = d2 * r * g0.z + b0.z; o0.w = d3 * r * g0.w + b0.w;
    o1.x = d4 * r * g1.x + b1.x; o1.y = d5 * r * g1.y + b1.y;
    o1.z = d6 * r * g1.z + b1.z; o1.w = d7 * r * g1.w + b1.w;
    *(ushort4*)(xbr + (l << 2)) = make_ushort4(f2h(o0.x), f2h(o0.y), f2h(o0.z), f2h(o0.w));
    *(ushort4*)(xbr + 256 + (l << 2)) = make_ushort4(f2h(o1.x), f2h(o1.y), f2h(o1.z), f2h(o1.w));
}

// ---------------- bilinear warp ----------------------------------------------
__global__ void warp_kernel(const float* __restrict__ x0, const float* __restrict__ shift,
                            const int* __restrict__ pms, float* __restrict__ warped) {
    int idx = blockIdx.x * 256 + threadIdx.x;
    if (idx >= M_ROWS * 512) return;
    int c = idx & 511;
    int m = idx >> 9;
    int t = m % NTOK;
    int b = m / NTOK;
    float max_shift = (float)pms[0];
    float sh = shift[m];
    float flow = sh * max_shift / 256.0f;
    float gx = 2.0f * ((float)c / 511.0f - 0.5f) + flow;
    float ix = ((gx + 1.0f) * 512.0f - 1.0f) * 0.5f;
    ix = fminf(fmaxf(ix, 0.0f), 511.0f);
    float gy = 2.0f * ((float)t / 180.0f - 0.5f);
    float iy = ((gy + 1.0f) * 181.0f - 1.0f) * 0.5f;
    iy = fminf(fmaxf(iy, 0.0f), 180.0f);
    float ix0f = floorf(ix), iy0f = floorf(iy);
    float wx = ix - ix0f, wy = iy - iy0f;
    int ix0 = min(max((int)ix0f, 0), 511);
    int ix1 = min(ix0 + 1, 511);
    int iy0 = min(max((int)iy0f, 0), 180);
    int iy1 = min(iy0 + 1, 180);
    const float* xb = x0 + (size_t)b * NTOK * 512;
    float v00 = xb[iy0 * 512 + ix0], v01 = xb[iy0 * 512 + ix1];
    float v10 = xb[iy1 * 512 + ix0], v11 = xb[iy1 * 512 + ix1];
    warped[idx] = (1.f - wy) * ((1.f - wx) * v00 + wx * v01) + wy * ((1.f - wx) * v10 + wx * v11);
}

extern "C" void kernel_launch(void* const* d_in, const int* in_sizes, int n_in,
                              void* d_out, int out_size, void* d_ws, size_t ws_size,
                              hipStream_t stream) {
    const float* x0   = (const float*)d_in[0];
    const int*   pms  = (const int*)d_in[1];
    const float* pos  = (const float*)d_in[2];
    const float* qkvw = (const float*)d_in[3];
    const float* qkvb = (const float*)d_in[4];
    const float* outw = (const float*)d_in[5];
    const float* outbp= (const float*)d_in[6];
    const float* relp = (const float*)d_in[7];
    const float* rpew = (const float*)d_in[8];
    const float* ln1g = (const float*)d_in[9];
    const float* ln1b = (const float*)d_in[10];
    const float* fw1  = (const float*)d_in[11];
    const float* fb1  = (const float*)d_in[12];
    const float* fw2  = (const float*)d_in[13];
    const float* fb2  = (const float*)d_in[14];
    const float* ln2g = (const float*)d_in[15];
    const float* ln2b = (const float*)d_in[16];
    const float* mw1  = (const float*)d_in[17];
    const float* mb1  = (const float*)d_in[18];
    const float* mw2  = (const float*)d_in[19];
    const float* mb2  = (const float*)d_in[20];

    float* out = (float*)d_out;

    char* ws = (char*)d_ws;
    ushort* xb    = (ushort*)(ws + 11862016);                 //  5,931,008 B (f16 residual)
    char*   qr    = ws + 11862016 + 5931008;
    ushort* ybuf  = (ushort*)qr;                              // f16 partial 0 (5.9MB)
    ushort* ybuf2 = (ushort*)(qr + 5931008);                  // f16 partial 1 (5.9MB)
    ushort* hbuf  = (ushort*)(qr + 11862016);                 // 23.7MB (ffn hidden)
    ushort* attnb = (ushort*)(qr + 35586048);                 //  5,931,008 B
    float*  rbias = (float*)(qr + 35586048 + 5931008);        //  6*512*4 B
    ushort* wts   = (ushort*)(qr + 35586048 + 5931008 + 12288);
    ushort* qkv_wt = wts;                                     // 6*1536*512
    ushort* out_wt = qkv_wt + 6 * 1536 * 512;                 // 6*512*512
    ushort* f1_wt  = out_wt + 6 * 512 * 512;                  // 6*2048*512
    ushort* f2_wt  = f1_wt  + 6 * 512 * 2048;                 // 6*512*2048
    ushort* w1t    = f2_wt  + 6 * 2048 * 512;                 // 64*512

    hipFuncSetAttribute((const void*)attn_fused,
                        hipFuncAttributeMaxDynamicSharedMemorySize, 124544);

    // single-dispatch prologue (5 transposes + rbias + add_pos)
    wt_all<<<7524, 256, 0, stream>>>(qkvw, outw, fw1, fw2, mw1, relp, rpew, x0, pos,
                                     qkv_wt, out_wt, f1_wt, f2_wt, w1t, rbias, xb);

    const int g_ffn1 = 96 * 16;        // BM=64, N=2048
    const int g_np4  = 96 * 4;         // BM=64, N=512
    for (int i = 0; i < NLAYER; ++i) {
        attn_fused<<<256, 384, 124544, stream>>>(xb, qkv_wt + (size_t)i * 1536 * 512,
                                                 qkvb + i * 1536, rbias + i * 512, attnb);
        mfma_gemm<64, 2, 2><<<g_np4 * 2, 256, 0, stream>>>(attnb, out_wt + (size_t)i * 512 * 512,
                                                           outbp + i * 512, ybuf, M_ROWS, 512, 512);
        lnres_kernel<2><<<1448, 256, 0, stream>>>(xb, ybuf, ybuf2, ln1g + i * 512, ln1b + i * 512);
        mfma_gemm<64, 1, 1><<<g_ffn1, 256, 0, stream>>>(xb, f1_wt + (size_t)i * 2048 * 512,
                                                        fb1 + i * 2048, hbuf, M_ROWS, 512, 2048);
        mfma_gemm<64, 2, 2><<<g_np4 * 2, 256, 0, stream>>>(hbuf, f2_wt + (size_t)i * 512 * 2048,
                                                           fb2 + i * 512, ybuf, M_ROWS, 2048, 512);
        lnres_kernel<2><<<1448, 256, 0, stream>>>(xb, ybuf, ybuf2, ln2g + i * 512, ln2b + i * 512);
    }

    head_mfma<<<46, 256, 0, stream>>>(xb, w1t, mb1, mw2, mb2, out);
    warp_kernel<<<(M_ROWS * 512 + 255) / 256, 256, 0, stream>>>(x0, out, pms, out + M_ROWS);
}